// Round 2
// baseline (661.292 us; speedup 1.0000x reference)
//
#include <hip/hip_runtime.h>
#include <hip/hip_bf16.h>
#include <cstdint>
#include <cstddef>

#define DI __device__ __forceinline__

typedef __attribute__((ext_vector_type(8))) short v8s;
typedef __attribute__((ext_vector_type(4))) float v4f;

DI void gload_lds16(const unsigned short* g, unsigned short* l) {
  __builtin_amdgcn_global_load_lds(
      (const __attribute__((address_space(1))) unsigned int*)g,
      (__attribute__((address_space(3))) unsigned int*)l, 16, 0, 0);
}

DI float bf2f(unsigned short u) { return __uint_as_float(((unsigned int)u) << 16); }
DI unsigned short f2bf(float f) {
  unsigned int u = __float_as_uint(f);
  u += 0x7FFFu + ((u >> 16) & 1u);
  return (unsigned short)(u >> 16);
}
DI unsigned int pack2(float a, float b) {
  return (unsigned int)f2bf(a) | ((unsigned int)f2bf(b) << 16);
}

// ------------- transpose+convert: in[R][C] fp32 -> out[C][R] bf16 -------------
__global__ __launch_bounds__(256) void transpose_cvt_k(
    const float* __restrict__ in, unsigned short* __restrict__ out, int R, int C) {
  __shared__ unsigned short t[32][33];
  const int j0 = blockIdx.x * 32, i0 = blockIdx.y * 32;
  const int tx = threadIdx.x & 31, ty = threadIdx.x >> 5;
#pragma unroll
  for (int r = 0; r < 32; r += 8) t[ty + r][tx] = f2bf(in[(size_t)(i0 + ty + r) * C + j0 + tx]);
  __syncthreads();
#pragma unroll
  for (int r = 0; r < 32; r += 8) out[(size_t)(j0 + ty + r) * R + i0 + tx] = t[tx][ty + r];
}

// V [T=8192,1024] bf16 -> VT [B*H][64 d][1024 s] bf16
__global__ __launch_bounds__(256) void vtrans_k(
    const unsigned short* __restrict__ v, unsigned short* __restrict__ vt) {
  __shared__ unsigned short t[32][33];
  const int bh = blockIdx.z, b = bh >> 4, h = bh & 15;
  const int s0 = blockIdx.x * 32, d0 = blockIdx.y * 32;
  const int tx = threadIdx.x & 31, ty = threadIdx.x >> 5;
  const unsigned short* src = v + ((size_t)(b * 1024 + s0)) * 1024 + h * 64 + d0;
#pragma unroll
  for (int r = 0; r < 32; r += 8) t[ty + r][tx] = src[(size_t)(ty + r) * 1024 + tx];
  __syncthreads();
  unsigned short* dst = vt + ((size_t)bh * 64 + d0) * 1024 + s0;
#pragma unroll
  for (int r = 0; r < 32; r += 8) dst[(size_t)(ty + r) * 1024 + tx] = t[tx][ty + r];
}

// ------------- LayerNorm: fp32 in, bf16 out, D=1024 -------------
__global__ __launch_bounds__(256) void ln_k(
    const float* __restrict__ x, const float* __restrict__ g,
    const float* __restrict__ b, unsigned short* __restrict__ out) {
  const int row = blockIdx.x;
  const float4 v = ((const float4*)(x + (size_t)row * 1024))[threadIdx.x];
  float s = v.x + v.y + v.z + v.w;
  float ss = v.x * v.x + v.y * v.y + v.z * v.z + v.w * v.w;
#pragma unroll
  for (int o = 1; o < 64; o <<= 1) { s += __shfl_xor(s, o); ss += __shfl_xor(ss, o); }
  __shared__ float red[8];
  const int wid = threadIdx.x >> 6, lane = threadIdx.x & 63;
  if (!lane) { red[wid] = s; red[4 + wid] = ss; }
  __syncthreads();
  s = red[0] + red[1] + red[2] + red[3];
  ss = red[4] + red[5] + red[6] + red[7];
  const float mean = s * (1.f / 1024.f);
  const float var = ss * (1.f / 1024.f) - mean * mean;
  const float rs = rsqrtf(var + 1e-5f);
  const float4 gv = ((const float4*)g)[threadIdx.x];
  const float4 bv = ((const float4*)b)[threadIdx.x];
  ushort4 ov;
  ov.x = f2bf((v.x - mean) * rs * gv.x + bv.x);
  ov.y = f2bf((v.y - mean) * rs * gv.y + bv.y);
  ov.z = f2bf((v.z - mean) * rs * gv.z + bv.z);
  ov.w = f2bf((v.w - mean) * rs * gv.w + bv.w);
  ((ushort4*)(out + (size_t)row * 1024))[threadIdx.x] = ov;
}

// ------------- GEMM: C[M,N] = epi(A[M,K] @ Bt[N,K]^T); A,Bt bf16; C fp32/bf16 -------------
enum { EPI_NONE = 0, EPI_BIAS_RES = 1, EPI_GELU = 2, EPI_RELU = 3, EPI_SCALE_BIAS = 4, EPI_FINAL = 5 };

template <int BN, int EPI, typename CT>
__global__ __launch_bounds__(256) void gemm_k(
    const unsigned short* __restrict__ A, const unsigned short* __restrict__ Bt,
    CT* __restrict__ C, const float* __restrict__ bias,
    const float* __restrict__ res, const float* __restrict__ extra,
    int M, int N, int K) {
  constexpr int BM = 128, BK = 32;
  constexpr int WN = (BN == 128) ? 2 : 1;
  constexpr int MR = (BN == 128) ? 4 : 2;
  constexpr int NR = 4;
  __shared__ unsigned short sA[BM * BK];
  __shared__ unsigned short sB[BN * BK];
  const int tid = threadIdx.x;
  const int lane = tid & 63, wid = tid >> 6;
  const int wm = wid / WN, wn = wid % WN;
  const int l15 = lane & 15, l4 = lane >> 4;
  const int row0 = blockIdx.x * BM, col0 = blockIdx.y * BN;
  v4f acc[MR][NR] = {};
  const int rowA = wm * MR * 16;
  const int rowB = wn * NR * 16;
  for (int k0 = 0; k0 < K; k0 += BK) {
#pragma unroll
    for (int r = 0; r < (BM * BK) / (256 * 8); ++r) {
      int e = (r * 256 + tid) * 8;
      gload_lds16(A + (size_t)(row0 + (e >> 5)) * K + k0 + (e & 31), ((unsigned short*)sA) + e);
    }
#pragma unroll
    for (int r = 0; r < (BN * BK) / (256 * 8); ++r) {
      int e = (r * 256 + tid) * 8;
      gload_lds16(Bt + (size_t)(col0 + (e >> 5)) * K + k0 + (e & 31), ((unsigned short*)sB) + e);
    }
    __syncthreads();
    v8s af[MR], bfr[NR];
#pragma unroll
    for (int m = 0; m < MR; ++m) af[m] = *(const v8s*)(sA + (rowA + m * 16 + l15) * BK + l4 * 8);
#pragma unroll
    for (int n = 0; n < NR; ++n) bfr[n] = *(const v8s*)(sB + (rowB + n * 16 + l15) * BK + l4 * 8);
#pragma unroll
    for (int m = 0; m < MR; ++m)
#pragma unroll
      for (int n = 0; n < NR; ++n)
        acc[m][n] = __builtin_amdgcn_mfma_f32_16x16x32_bf16(af[m], bfr[n], acc[m][n], 0, 0, 0);
    __syncthreads();
  }
#pragma unroll
  for (int m = 0; m < MR; ++m) {
#pragma unroll
    for (int n = 0; n < NR; ++n) {
      const int col = col0 + rowB + n * 16 + l15;
      float bv = 0.f;
      if (EPI != EPI_NONE) bv = bias[col];
#pragma unroll
      for (int j = 0; j < 4; ++j) {
        const int row = row0 + rowA + m * 16 + l4 * 4 + j;
        const size_t idx = (size_t)row * N + col;
        float v = acc[m][n][j];
        if (EPI == EPI_BIAS_RES) v += bv + res[idx];
        else if (EPI == EPI_GELU) { v += bv; v = 0.5f * v * (1.f + erff(v * 0.70710678118f)); }
        else if (EPI == EPI_RELU) { v += bv; v = fmaxf(v, 0.f); }
        else if (EPI == EPI_SCALE_BIAS) { v = (v + bv) * 0.1f; }
        else if (EPI == EPI_FINAL) { v += bv + res[idx] + extra[idx]; }
        if constexpr (sizeof(CT) == 2) C[idx] = f2bf(v); else C[idx] = v;
      }
    }
  }
}

// ------------- flash attention, swapped-QK^T, 4 waves x 16 q-rows (all bf16) -------------
__global__ __launch_bounds__(256) void attn_k(
    const unsigned short* __restrict__ Q, const unsigned short* __restrict__ Kc,
    const unsigned short* __restrict__ VT, unsigned short* __restrict__ O) {
  const int bh = blockIdx.y, b = bh >> 4, h = bh & 15;
  const int q0 = blockIdx.x * 64;
  const int tid = threadIdx.x, lane = tid & 63, wid = tid >> 6;
  const int l15 = lane & 15, l4 = lane >> 4;
  __shared__ unsigned short sQ[64 * 64];
  __shared__ unsigned short sK[32 * 64];
  __shared__ unsigned short sV[64 * 32];
  const unsigned short* Qb = Q + ((size_t)(b * 1024 + q0)) * 1024 + h * 64;
  const unsigned short* Kb = Kc + ((size_t)(b * 1024)) * 1024 + h * 64;
  const unsigned short* Vb = VT + (size_t)bh * 64 * 1024;
#pragma unroll
  for (int r = 0; r < 2; ++r) {  // stage Q, source-swizzled (granule ^= row&7)
    int e = (r * 256 + tid) * 8, qr = e >> 6, gs = ((e >> 3) & 7) ^ (qr & 7);
    gload_lds16(Qb + (size_t)qr * 1024 + gs * 8, ((unsigned short*)sQ) + e);
  }
  float m_run = -3e38f, l_run = 0.f;
  v4f oacc[4] = {};
  const int qrow = wid * 16 + l15;
  for (int k0 = 0; k0 < 1024; k0 += 32) {
    { int e = tid * 8, kr = e >> 6, gs = ((e >> 3) & 7) ^ (kr & 7);
      gload_lds16(Kb + (size_t)(k0 + kr) * 1024 + gs * 8, ((unsigned short*)sK) + e); }
    { int e = tid * 8, dr = e >> 5, gs = ((e >> 3) & 3) ^ (dr & 3) ^ ((dr >> 2) & 3);
      gload_lds16(Vb + (size_t)dr * 1024 + k0 + gs * 8, ((unsigned short*)sV) + e); }
    __syncthreads();
    // S^T[key][q] = K . Q^T : lane holds q=l15, keys {kc*16 + 4*l4 + j}
    v4f sc0 = {}, sc1 = {};
#pragma unroll
    for (int dh = 0; dh < 2; ++dh) {
      const int ga0 = (l4 + 4 * dh) ^ (l15 & 7);
      v8s a0 = *(const v8s*)(sK + l15 * 64 + ga0 * 8);
      const int kr1 = 16 + l15;
      const int ga1 = (l4 + 4 * dh) ^ (kr1 & 7);
      v8s a1 = *(const v8s*)(sK + kr1 * 64 + ga1 * 8);
      const int gb = (l4 + 4 * dh) ^ (qrow & 7);
      v8s bq = *(const v8s*)(sQ + qrow * 64 + gb * 8);
      sc0 = __builtin_amdgcn_mfma_f32_16x16x32_bf16(a0, bq, sc0, 0, 0, 0);
      sc1 = __builtin_amdgcn_mfma_f32_16x16x32_bf16(a1, bq, sc1, 0, 0, 0);
    }
    float s8[8];
    float smax = -3e38f;
#pragma unroll
    for (int j = 0; j < 4; ++j) { s8[j] = sc0[j] * 0.125f; s8[4 + j] = sc1[j] * 0.125f; }
#pragma unroll
    for (int i = 0; i < 8; ++i) smax = fmaxf(smax, s8[i]);
    smax = fmaxf(smax, __shfl_xor(smax, 16));
    smax = fmaxf(smax, __shfl_xor(smax, 32));
    const float m_new = fmaxf(m_run, smax);
    const float fac = __expf(m_run - m_new);
    float tsum = 0.f;
#pragma unroll
    for (int i = 0; i < 8; ++i) { s8[i] = __expf(s8[i] - m_new); tsum += s8[i]; }
    tsum += __shfl_xor(tsum, 16);
    tsum += __shfl_xor(tsum, 32);
    l_run = l_run * fac + tsum;
    m_run = m_new;
#pragma unroll
    for (int nb = 0; nb < 4; ++nb) {
      oacc[nb][0] *= fac; oacc[nb][1] *= fac; oacc[nb][2] *= fac; oacc[nb][3] *= fac;
    }
    // redistribute P^T to B-operand layout (lane needs keys 8*l4..8*l4+7 at q=l15)
    const unsigned int w0 = pack2(s8[0], s8[1]), w1 = pack2(s8[2], s8[3]);
    const unsigned int w2 = pack2(s8[4], s8[5]), w3 = pack2(s8[6], s8[7]);
    const int cse = l4 >> 1;
    const int src0 = l15 + 32 * (l4 & 1);
    const int src1 = src0 + 16;
    const unsigned int t00 = __shfl((int)w0, src0), t20 = __shfl((int)w2, src0);
    const unsigned int t10 = __shfl((int)w1, src0), t30 = __shfl((int)w3, src0);
    const unsigned int t01 = __shfl((int)w0, src1), t21 = __shfl((int)w2, src1);
    const unsigned int t11 = __shfl((int)w1, src1), t31 = __shfl((int)w3, src1);
    union { unsigned int u[4]; v8s v; } pb;
    pb.u[0] = cse ? t20 : t00; pb.u[1] = cse ? t30 : t10;
    pb.u[2] = cse ? t21 : t01; pb.u[3] = cse ? t31 : t11;
    // O^T[d][q] += V^T . P^T
#pragma unroll
    for (int nb = 0; nb < 4; ++nb) {
      const int drow = nb * 16 + l15;
      const int gv = l4 ^ (drow & 3) ^ ((drow >> 2) & 3);
      v8s vf = *(const v8s*)(sV + drow * 32 + gv * 8);
      oacc[nb] = __builtin_amdgcn_mfma_f32_16x16x32_bf16(vf, pb.v, oacc[nb], 0, 0, 0);
    }
    __syncthreads();
  }
  const float inv = 1.f / l_run;
  unsigned short* Or = O + ((size_t)(b * 1024 + q0 + wid * 16 + l15)) * 1024 + h * 64;
#pragma unroll
  for (int nb = 0; nb < 4; ++nb) {
    ushort4 st;
    st.x = f2bf(oacc[nb][0] * inv); st.y = f2bf(oacc[nb][1] * inv);
    st.z = f2bf(oacc[nb][2] * inv); st.w = f2bf(oacc[nb][3] * inv);
    *(ushort4*)(Or + nb * 16 + l4 * 4) = st;
  }
}

// ---------------- launch ----------------
extern "C" void kernel_launch(void* const* d_in, const int* in_sizes, int n_in,
                              void* d_out, int out_size, void* d_ws, size_t ws_size,
                              hipStream_t stream) {
  (void)in_sizes; (void)n_in; (void)out_size;
  const float* x    = (const float*)d_in[0];
  const float* ln1g = (const float*)d_in[1];
  const float* ln1b = (const float*)d_in[2];
  const float* wq   = (const float*)d_in[3];
  const float* wk   = (const float*)d_in[4];
  const float* wv   = (const float*)d_in[5];
  const float* wo   = (const float*)d_in[6];
  const float* bo   = (const float*)d_in[7];
  const float* ln2g = (const float*)d_in[8];
  const float* ln2b = (const float*)d_in[9];
  const float* w1   = (const float*)d_in[10];
  const float* b1   = (const float*)d_in[11];
  const float* w2   = (const float*)d_in[12];
  const float* b2   = (const float*)d_in[13];
  const float* alng = (const float*)d_in[14];
  const float* alnb = (const float*)d_in[15];
  const float* wd   = (const float*)d_in[16];
  const float* bd   = (const float*)d_in[17];
  const float* wu   = (const float*)d_in[18];
  const float* bu   = (const float*)d_in[19];
  float* out = (float*)d_out;

  char* W = (char*)d_ws;
  size_t off = 0;
  auto allocB = [&](size_t bytes) { void* p = W + off; off += (bytes + 255) & ~(size_t)255; return p; };
  const size_t T = 8192;  // B*S
  unsigned short* wqt = (unsigned short*)allocB(1024 * 1024 * 2);
  unsigned short* wkt = (unsigned short*)allocB(1024 * 1024 * 2);
  unsigned short* wvt = (unsigned short*)allocB(1024 * 1024 * 2);
  unsigned short* wot = (unsigned short*)allocB(1024 * 1024 * 2);
  unsigned short* w1t = (unsigned short*)allocB((size_t)4096 * 1024 * 2);
  unsigned short* w2t = (unsigned short*)allocB((size_t)4096 * 1024 * 2);
  unsigned short* wdt = (unsigned short*)allocB(64 * 1024 * 2);
  unsigned short* wut = (unsigned short*)allocB(64 * 1024 * 2);
  unsigned short* H   = (unsigned short*)allocB(T * 1024 * 2);
  unsigned short* Qb  = (unsigned short*)allocB(T * 1024 * 2);
  unsigned short* Kb  = (unsigned short*)allocB(T * 1024 * 2);  // adjacent to Qb
  unsigned short* Vb  = (unsigned short*)allocB(T * 1024 * 2);
  unsigned short* VT  = (unsigned short*)allocB(T * 1024 * 2);
  float* X2           = (float*)allocB(T * 1024 * 4);
  unsigned short* MID = (unsigned short*)allocB(T * 4096 * 2);
  // overlays (dead buffers):
  unsigned short* DWN = VT;          // 8192x64 bf16, VT dead after attention
  float* ADP          = (float*)Qb;  // 8192x1024 fp32 spans Qb+Kb (contiguous), dead after attention
  if (ws_size < off) return;  // scratch too small: output untouched -> visible 5.94 absmax

  dim3 blk(256);
  transpose_cvt_k<<<dim3(32, 32), blk, 0, stream>>>(wq, wqt, 1024, 1024);
  transpose_cvt_k<<<dim3(32, 32), blk, 0, stream>>>(wk, wkt, 1024, 1024);
  transpose_cvt_k<<<dim3(32, 32), blk, 0, stream>>>(wv, wvt, 1024, 1024);
  transpose_cvt_k<<<dim3(32, 32), blk, 0, stream>>>(wo, wot, 1024, 1024);
  transpose_cvt_k<<<dim3(128, 32), blk, 0, stream>>>(w1, w1t, 1024, 4096);
  transpose_cvt_k<<<dim3(32, 128), blk, 0, stream>>>(w2, w2t, 4096, 1024);
  transpose_cvt_k<<<dim3(2, 32), blk, 0, stream>>>(wd, wdt, 1024, 64);
  transpose_cvt_k<<<dim3(32, 2), blk, 0, stream>>>(wu, wut, 64, 1024);

  ln_k<<<8192, blk, 0, stream>>>(x, ln1g, ln1b, H);
  gemm_k<128, EPI_NONE, unsigned short><<<dim3(64, 8), blk, 0, stream>>>(H, wqt, Qb, nullptr, nullptr, nullptr, 8192, 1024, 1024);
  gemm_k<128, EPI_NONE, unsigned short><<<dim3(64, 8), blk, 0, stream>>>(H, wkt, Kb, nullptr, nullptr, nullptr, 8192, 1024, 1024);
  gemm_k<128, EPI_NONE, unsigned short><<<dim3(64, 8), blk, 0, stream>>>(H, wvt, Vb, nullptr, nullptr, nullptr, 8192, 1024, 1024);
  vtrans_k<<<dim3(32, 2, 128), blk, 0, stream>>>(Vb, VT);
  attn_k<<<dim3(16, 128), blk, 0, stream>>>(Qb, Kb, VT, Vb);  // attn out -> Vb
  gemm_k<128, EPI_BIAS_RES, float><<<dim3(64, 8), blk, 0, stream>>>(Vb, wot, X2, bo, x, nullptr, 8192, 1024, 1024);
  ln_k<<<8192, blk, 0, stream>>>(X2, alng, alnb, H);
  gemm_k<64, EPI_RELU, unsigned short><<<dim3(64, 1), blk, 0, stream>>>(H, wdt, DWN, bd, nullptr, nullptr, 8192, 64, 1024);
  gemm_k<128, EPI_SCALE_BIAS, float><<<dim3(64, 8), blk, 0, stream>>>(DWN, wut, ADP, bu, nullptr, nullptr, 8192, 1024, 64);
  ln_k<<<8192, blk, 0, stream>>>(X2, ln2g, ln2b, H);
  gemm_k<128, EPI_GELU, unsigned short><<<dim3(64, 32), blk, 0, stream>>>(H, w1t, MID, b1, nullptr, nullptr, 8192, 4096, 1024);
  gemm_k<128, EPI_FINAL, float><<<dim3(64, 8), blk, 0, stream>>>(MID, w2t, out, b2, X2, ADP, 8192, 1024, 4096);
}

// Round 3
// 613.417 us; speedup vs baseline: 1.0780x; 1.0780x over previous
//
#include <hip/hip_runtime.h>
#include <hip/hip_bf16.h>
#include <cstdint>
#include <cstddef>

#define DI __device__ __forceinline__

typedef __attribute__((ext_vector_type(8))) short v8s;
typedef __attribute__((ext_vector_type(4))) float v4f;

DI void gload_lds16(const unsigned short* g, unsigned short* l) {
  __builtin_amdgcn_global_load_lds(
      (const __attribute__((address_space(1))) unsigned int*)g,
      (__attribute__((address_space(3))) unsigned int*)l, 16, 0, 0);
}

DI float bf2f(unsigned short u) { return __uint_as_float(((unsigned int)u) << 16); }
DI unsigned short f2bf(float f) {
  unsigned int u = __float_as_uint(f);
  u += 0x7FFFu + ((u >> 16) & 1u);
  return (unsigned short)(u >> 16);
}
DI unsigned int pack2(float a, float b) {
  return (unsigned int)f2bf(a) | ((unsigned int)f2bf(b) << 16);
}

// ------------- transpose+convert: in[R][C] fp32 -> out[C][R] bf16 -------------
__global__ __launch_bounds__(256) void transpose_cvt_k(
    const float* __restrict__ in, unsigned short* __restrict__ out, int R, int C) {
  __shared__ unsigned short t[32][33];
  const int j0 = blockIdx.x * 32, i0 = blockIdx.y * 32;
  const int tx = threadIdx.x & 31, ty = threadIdx.x >> 5;
#pragma unroll
  for (int r = 0; r < 32; r += 8) t[ty + r][tx] = f2bf(in[(size_t)(i0 + ty + r) * C + j0 + tx]);
  __syncthreads();
#pragma unroll
  for (int r = 0; r < 32; r += 8) out[(size_t)(j0 + ty + r) * R + i0 + tx] = t[tx][ty + r];
}

// V region [T=8192, ld] bf16 -> VT [B*H][64 d][1024 s] bf16
__global__ __launch_bounds__(256) void vtrans_k(
    const unsigned short* __restrict__ v, unsigned short* __restrict__ vt, int ld) {
  __shared__ unsigned short t[32][33];
  const int bh = blockIdx.z, b = bh >> 4, h = bh & 15;
  const int s0 = blockIdx.x * 32, d0 = blockIdx.y * 32;
  const int tx = threadIdx.x & 31, ty = threadIdx.x >> 5;
  const unsigned short* src = v + (size_t)(b * 1024 + s0) * ld + h * 64 + d0;
#pragma unroll
  for (int r = 0; r < 32; r += 8) t[ty + r][tx] = src[(size_t)(ty + r) * ld + tx];
  __syncthreads();
  unsigned short* dst = vt + ((size_t)bh * 64 + d0) * 1024 + s0;
#pragma unroll
  for (int r = 0; r < 32; r += 8) dst[(size_t)(ty + r) * 1024 + tx] = t[tx][ty + r];
}

// ------------- LayerNorm: fp32 in, bf16 out, D=1024 -------------
__global__ __launch_bounds__(256) void ln_k(
    const float* __restrict__ x, const float* __restrict__ g,
    const float* __restrict__ b, unsigned short* __restrict__ out) {
  const int row = blockIdx.x;
  const float4 v = ((const float4*)(x + (size_t)row * 1024))[threadIdx.x];
  float s = v.x + v.y + v.z + v.w;
  float ss = v.x * v.x + v.y * v.y + v.z * v.z + v.w * v.w;
#pragma unroll
  for (int o = 1; o < 64; o <<= 1) { s += __shfl_xor(s, o); ss += __shfl_xor(ss, o); }
  __shared__ float red[8];
  const int wid = threadIdx.x >> 6, lane = threadIdx.x & 63;
  if (!lane) { red[wid] = s; red[4 + wid] = ss; }
  __syncthreads();
  s = red[0] + red[1] + red[2] + red[3];
  ss = red[4] + red[5] + red[6] + red[7];
  const float mean = s * (1.f / 1024.f);
  const float var = ss * (1.f / 1024.f) - mean * mean;
  const float rs = rsqrtf(var + 1e-5f);
  const float4 gv = ((const float4*)g)[threadIdx.x];
  const float4 bv = ((const float4*)b)[threadIdx.x];
  ushort4 ov;
  ov.x = f2bf((v.x - mean) * rs * gv.x + bv.x);
  ov.y = f2bf((v.y - mean) * rs * gv.y + bv.y);
  ov.z = f2bf((v.z - mean) * rs * gv.z + bv.z);
  ov.w = f2bf((v.w - mean) * rs * gv.w + bv.w);
  ((ushort4*)(out + (size_t)row * 1024))[threadIdx.x] = ov;
}

enum { EPI_NONE = 0, EPI_BIAS_RES = 1, EPI_GELU = 2, EPI_RELU = 3, EPI_SCALE_BIAS = 4, EPI_FINAL = 5 };

// ======= 8-phase 8-wave GEMM (T2 swizzle + T3/T4 counted vmcnt + T5 setprio) =======
// C[M,N] = epi(A[M,K] @ Bt[N,K]^T). BK=64, waves 2x4, per-wave tile (BM/2)x(BN/4).
template <int BM, int BN, int EPI, typename CT>
__global__ __launch_bounds__(512, 2) void gemm8_k(
    const unsigned short* __restrict__ A, const unsigned short* __restrict__ Bt,
    CT* __restrict__ C, const float* __restrict__ bias,
    const float* __restrict__ res, const float* __restrict__ extra,
    int M, int N, int K, int gm, int gn) {
  constexpr int MF = BM / 32, NF = BN / 64, MPP = MF / 4;
  constexpr int LA = BM / 64, LB = BN / 64, LT = LA + LB;
  constexpr int BUFE = (BM + BN) * 64;  // elems per K-tile buffer (A | B)
  __shared__ unsigned short lds[BUFE * 2];
  const int tid = threadIdx.x;
  const int lane = tid & 63, wid = tid >> 6;
  const int wm = wid >> 2, wn = wid & 3;
  const int l15 = lane & 15, l4 = lane >> 4;
  const int nwg = gm * gn;
  const int bid = blockIdx.x;
  const int swz = (bid % 8) * (nwg / 8) + bid / 8;  // XCD swizzle (nwg % 8 == 0)
  const int row0 = (swz / gn) * BM, col0 = (swz % gn) * BN;
  const int NT = K >> 6;

  const int srow = tid >> 3, sgr = tid & 7;  // staging: 8 threads/row, 16B granules
  // T2: LDS dest linear; global SOURCE pre-swizzled with granule ^= (row&7)
  auto stA = [&](int kt, int b, int a) {
    const unsigned short* s = A + (size_t)(row0 + a * 64 + srow) * K + kt * 64 + ((sgr ^ (srow & 7)) << 3);
    gload_lds16(s, lds + b * BUFE + a * 4096 + tid * 8);
  };
  auto stB = [&](int kt, int b, int a) {
    const unsigned short* s = Bt + (size_t)(col0 + a * 64 + srow) * K + kt * 64 + ((sgr ^ (srow & 7)) << 3);
    gload_lds16(s, lds + b * BUFE + BM * 64 + a * 4096 + tid * 8);
  };

  // prologue: tile0 A+B, tile1 B (tile1 A issued during tile0 phases)
#pragma unroll
  for (int e = 0; e < LA; ++e) stA(0, 0, e);
#pragma unroll
  for (int e = 0; e < LB; ++e) stB(0, 0, e);
#pragma unroll
  for (int e = 0; e < LB; ++e) stB(1, 1, e);
  asm volatile("s_waitcnt vmcnt(%0)" ::"n"(LB) : "memory");
  __builtin_amdgcn_s_barrier();

  v4f acc[MF][NF] = {};
  v8s bfr[NF][2];
  for (int t = 0; t < NT; ++t) {
    const int buf = t & 1;
    const unsigned short* La = lds + buf * BUFE;
    const unsigned short* Lb = lds + buf * BUFE + BM * 64;
#pragma unroll
    for (int p = 0; p < 4; ++p) {
      if (p == 0) {  // B-frags for whole K-tile (consumed -> B region free after phase 0)
#pragma unroll
        for (int nf = 0; nf < NF; ++nf) {
          const int r = wn * (BN / 4) + nf * 16 + l15;
#pragma unroll
          for (int kk = 0; kk < 2; ++kk)
            bfr[nf][kk] = *(const v8s*)(Lb + r * 64 + ((kk * 32 + l4 * 8) ^ ((r & 7) << 3)));
        }
      }
      v8s af[MPP][2];
#pragma unroll
      for (int mm = 0; mm < MPP; ++mm) {
        const int r = wm * (BM / 2) + (p * MPP + mm) * 16 + l15;
#pragma unroll
        for (int kk = 0; kk < 2; ++kk)
          af[mm][kk] = *(const v8s*)(La + r * 64 + ((kk * 32 + l4 * 8) ^ ((r & 7) << 3)));
      }
      // stage: entries [p*LT/4,(p+1)*LT/4); first LA = A(t+1)->buf^1, then LB = B(t+2)->buf
#pragma unroll
      for (int e = p * LT / 4; e < (p + 1) * LT / 4; ++e) {
        if (e < LA) { if (t + 1 < NT) stA(t + 1, buf ^ 1, e); }
        else        { if (t + 2 < NT) stB(t + 2, buf, e - LA); }
      }
      __builtin_amdgcn_s_barrier();
      asm volatile("s_waitcnt lgkmcnt(0)" ::: "memory");
      __builtin_amdgcn_s_setprio(1);
#pragma unroll
      for (int mm = 0; mm < MPP; ++mm)
#pragma unroll
        for (int nf = 0; nf < NF; ++nf)
#pragma unroll
          for (int kk = 0; kk < 2; ++kk)
            acc[p * MPP + mm][nf] = __builtin_amdgcn_mfma_f32_16x16x32_bf16(
                af[mm][kk], bfr[nf][kk], acc[p * MPP + mm][nf], 0, 0, 0);
      __builtin_amdgcn_s_setprio(0);
      if (p == 3 && t + 1 < NT) {  // counted boundary wait (never 0 mid-loop)
        if (t + 2 < NT) asm volatile("s_waitcnt vmcnt(%0)" ::"n"(LB) : "memory");
        else            asm volatile("s_waitcnt vmcnt(0)" ::: "memory");
      }
      __builtin_amdgcn_s_barrier();
    }
  }

#pragma unroll
  for (int mf = 0; mf < MF; ++mf) {
#pragma unroll
    for (int nf = 0; nf < NF; ++nf) {
      const int col = col0 + wn * (BN / 4) + nf * 16 + l15;
      float bv = 0.f;
      if (EPI != EPI_NONE) bv = bias[col];
#pragma unroll
      for (int j = 0; j < 4; ++j) {
        const int row = row0 + wm * (BM / 2) + mf * 16 + l4 * 4 + j;
        const size_t idx = (size_t)row * N + col;
        float v = acc[mf][nf][j];
        if (EPI == EPI_BIAS_RES) v += bv + res[idx];
        else if (EPI == EPI_GELU) { v += bv; v = 0.5f * v * (1.f + erff(v * 0.70710678118f)); }
        else if (EPI == EPI_RELU) { v += bv; v = fmaxf(v, 0.f); }
        else if (EPI == EPI_SCALE_BIAS) { v = (v + bv) * 0.1f; }
        else if (EPI == EPI_FINAL) { v += bv + res[idx] + extra[idx]; }
        if constexpr (sizeof(CT) == 2) C[idx] = f2bf(v); else C[idx] = v;
      }
    }
  }
}

// ------------- small 2-phase GEMM (adapters: N=64 / K=64) -------------
template <int BN, int EPI, typename CT>
__global__ __launch_bounds__(256) void gemm_k(
    const unsigned short* __restrict__ A, const unsigned short* __restrict__ Bt,
    CT* __restrict__ C, const float* __restrict__ bias,
    const float* __restrict__ res, const float* __restrict__ extra,
    int M, int N, int K) {
  constexpr int BM = 128, BK = 32;
  constexpr int WN = (BN == 128) ? 2 : 1;
  constexpr int MR = (BN == 128) ? 4 : 2;
  constexpr int NR = 4;
  __shared__ unsigned short sA[BM * BK];
  __shared__ unsigned short sB[BN * BK];
  const int tid = threadIdx.x;
  const int lane = tid & 63, wid = tid >> 6;
  const int wm = wid / WN, wn = wid % WN;
  const int l15 = lane & 15, l4 = lane >> 4;
  const int row0 = blockIdx.x * BM, col0 = blockIdx.y * BN;
  v4f acc[MR][NR] = {};
  const int rowA = wm * MR * 16;
  const int rowB = wn * NR * 16;
  for (int k0 = 0; k0 < K; k0 += BK) {
#pragma unroll
    for (int r = 0; r < (BM * BK) / (256 * 8); ++r) {
      int e = (r * 256 + tid) * 8;
      gload_lds16(A + (size_t)(row0 + (e >> 5)) * K + k0 + (e & 31), ((unsigned short*)sA) + e);
    }
#pragma unroll
    for (int r = 0; r < (BN * BK) / (256 * 8); ++r) {
      int e = (r * 256 + tid) * 8;
      gload_lds16(Bt + (size_t)(col0 + (e >> 5)) * K + k0 + (e & 31), ((unsigned short*)sB) + e);
    }
    __syncthreads();
    v8s af[MR], bfr2[NR];
#pragma unroll
    for (int m = 0; m < MR; ++m) af[m] = *(const v8s*)(sA + (rowA + m * 16 + l15) * BK + l4 * 8);
#pragma unroll
    for (int n = 0; n < NR; ++n) bfr2[n] = *(const v8s*)(sB + (rowB + n * 16 + l15) * BK + l4 * 8);
#pragma unroll
    for (int m = 0; m < MR; ++m)
#pragma unroll
      for (int n = 0; n < NR; ++n)
        acc[m][n] = __builtin_amdgcn_mfma_f32_16x16x32_bf16(af[m], bfr2[n], acc[m][n], 0, 0, 0);
    __syncthreads();
  }
#pragma unroll
  for (int m = 0; m < MR; ++m) {
#pragma unroll
    for (int n = 0; n < NR; ++n) {
      const int col = col0 + rowB + n * 16 + l15;
      float bv = 0.f;
      if (EPI != EPI_NONE) bv = bias[col];
#pragma unroll
      for (int j = 0; j < 4; ++j) {
        const int row = row0 + rowA + m * 16 + l4 * 4 + j;
        const size_t idx = (size_t)row * N + col;
        float v = acc[m][n][j];
        if (EPI == EPI_BIAS_RES) v += bv + res[idx];
        else if (EPI == EPI_GELU) { v += bv; v = 0.5f * v * (1.f + erff(v * 0.70710678118f)); }
        else if (EPI == EPI_RELU) { v += bv; v = fmaxf(v, 0.f); }
        else if (EPI == EPI_SCALE_BIAS) { v = (v + bv) * 0.1f; }
        else if (EPI == EPI_FINAL) { v += bv + res[idx] + extra[idx]; }
        if constexpr (sizeof(CT) == 2) C[idx] = f2bf(v); else C[idx] = v;
      }
    }
  }
}

// ------------- flash attention, swapped-QK^T, 4 waves x 16 q-rows (bf16) -------------
__global__ __launch_bounds__(256) void attn_k(
    const unsigned short* __restrict__ Q, const unsigned short* __restrict__ Kc,
    const unsigned short* __restrict__ VT, unsigned short* __restrict__ O, int ldqk) {
  const int bh = blockIdx.y, b = bh >> 4, h = bh & 15;
  const int q0 = blockIdx.x * 64;
  const int tid = threadIdx.x, lane = tid & 63, wid = tid >> 6;
  const int l15 = lane & 15, l4 = lane >> 4;
  __shared__ unsigned short sQ[64 * 64];
  __shared__ unsigned short sK[32 * 64];
  __shared__ unsigned short sV[64 * 32];
  const unsigned short* Qb = Q + (size_t)(b * 1024 + q0) * ldqk + h * 64;
  const unsigned short* Kb = Kc + (size_t)(b * 1024) * ldqk + h * 64;
  const unsigned short* Vb = VT + (size_t)bh * 64 * 1024;
#pragma unroll
  for (int r = 0; r < 2; ++r) {  // stage Q, source-swizzled (granule ^= row&7)
    int e = (r * 256 + tid) * 8, qr = e >> 6, gs = ((e >> 3) & 7) ^ (qr & 7);
    gload_lds16(Qb + (size_t)qr * ldqk + gs * 8, ((unsigned short*)sQ) + e);
  }
  float m_run = -3e38f, l_run = 0.f;
  v4f oacc[4] = {};
  const int qrow = wid * 16 + l15;
  for (int k0 = 0; k0 < 1024; k0 += 32) {
    { int e = tid * 8, kr = e >> 6, gs = ((e >> 3) & 7) ^ (kr & 7);
      gload_lds16(Kb + (size_t)(k0 + kr) * ldqk + gs * 8, ((unsigned short*)sK) + e); }
    { int e = tid * 8, dr = e >> 5, gs = ((e >> 3) & 3) ^ (dr & 3) ^ ((dr >> 2) & 3);
      gload_lds16(Vb + (size_t)dr * 1024 + k0 + gs * 8, ((unsigned short*)sV) + e); }
    __syncthreads();
    v4f sc0 = {}, sc1 = {};
#pragma unroll
    for (int dh = 0; dh < 2; ++dh) {
      const int ga0 = (l4 + 4 * dh) ^ (l15 & 7);
      v8s a0 = *(const v8s*)(sK + l15 * 64 + ga0 * 8);
      const int kr1 = 16 + l15;
      const int ga1 = (l4 + 4 * dh) ^ (kr1 & 7);
      v8s a1 = *(const v8s*)(sK + kr1 * 64 + ga1 * 8);
      const int gb = (l4 + 4 * dh) ^ (qrow & 7);
      v8s bq = *(const v8s*)(sQ + qrow * 64 + gb * 8);
      sc0 = __builtin_amdgcn_mfma_f32_16x16x32_bf16(a0, bq, sc0, 0, 0, 0);
      sc1 = __builtin_amdgcn_mfma_f32_16x16x32_bf16(a1, bq, sc1, 0, 0, 0);
    }
    float s8[8];
    float smax = -3e38f;
#pragma unroll
    for (int j = 0; j < 4; ++j) { s8[j] = sc0[j] * 0.125f; s8[4 + j] = sc1[j] * 0.125f; }
#pragma unroll
    for (int i = 0; i < 8; ++i) smax = fmaxf(smax, s8[i]);
    smax = fmaxf(smax, __shfl_xor(smax, 16));
    smax = fmaxf(smax, __shfl_xor(smax, 32));
    const float m_new = fmaxf(m_run, smax);
    const float fac = __expf(m_run - m_new);
    float tsum = 0.f;
#pragma unroll
    for (int i = 0; i < 8; ++i) { s8[i] = __expf(s8[i] - m_new); tsum += s8[i]; }
    tsum += __shfl_xor(tsum, 16);
    tsum += __shfl_xor(tsum, 32);
    l_run = l_run * fac + tsum;
    m_run = m_new;
#pragma unroll
    for (int nb = 0; nb < 4; ++nb) {
      oacc[nb][0] *= fac; oacc[nb][1] *= fac; oacc[nb][2] *= fac; oacc[nb][3] *= fac;
    }
    const unsigned int w0 = pack2(s8[0], s8[1]), w1 = pack2(s8[2], s8[3]);
    const unsigned int w2 = pack2(s8[4], s8[5]), w3 = pack2(s8[6], s8[7]);
    const int cse = l4 >> 1;
    const int src0 = l15 + 32 * (l4 & 1);
    const int src1 = src0 + 16;
    const unsigned int t00 = __shfl((int)w0, src0), t20 = __shfl((int)w2, src0);
    const unsigned int t10 = __shfl((int)w1, src0), t30 = __shfl((int)w3, src0);
    const unsigned int t01 = __shfl((int)w0, src1), t21 = __shfl((int)w2, src1);
    const unsigned int t11 = __shfl((int)w1, src1), t31 = __shfl((int)w3, src1);
    union { unsigned int u[4]; v8s v; } pb;
    pb.u[0] = cse ? t20 : t00; pb.u[1] = cse ? t30 : t10;
    pb.u[2] = cse ? t21 : t01; pb.u[3] = cse ? t31 : t11;
#pragma unroll
    for (int nb = 0; nb < 4; ++nb) {
      const int drow = nb * 16 + l15;
      const int gv = l4 ^ (drow & 3) ^ ((drow >> 2) & 3);
      v8s vf = *(const v8s*)(sV + drow * 32 + gv * 8);
      oacc[nb] = __builtin_amdgcn_mfma_f32_16x16x32_bf16(vf, pb.v, oacc[nb], 0, 0, 0);
    }
    __syncthreads();
  }
  const float inv = 1.f / l_run;
  unsigned short* Or = O + (size_t)(b * 1024 + q0 + wid * 16 + l15) * 1024 + h * 64;
#pragma unroll
  for (int nb = 0; nb < 4; ++nb) {
    ushort4 st;
    st.x = f2bf(oacc[nb][0] * inv); st.y = f2bf(oacc[nb][1] * inv);
    st.z = f2bf(oacc[nb][2] * inv); st.w = f2bf(oacc[nb][3] * inv);
    *(ushort4*)(Or + nb * 16 + l4 * 4) = st;
  }
}

// ---------------- launch ----------------
extern "C" void kernel_launch(void* const* d_in, const int* in_sizes, int n_in,
                              void* d_out, int out_size, void* d_ws, size_t ws_size,
                              hipStream_t stream) {
  (void)in_sizes; (void)n_in; (void)out_size;
  const float* x    = (const float*)d_in[0];
  const float* ln1g = (const float*)d_in[1];
  const float* ln1b = (const float*)d_in[2];
  const float* wq   = (const float*)d_in[3];
  const float* wk   = (const float*)d_in[4];
  const float* wv   = (const float*)d_in[5];
  const float* wo   = (const float*)d_in[6];
  const float* bo   = (const float*)d_in[7];
  const float* ln2g = (const float*)d_in[8];
  const float* ln2b = (const float*)d_in[9];
  const float* w1   = (const float*)d_in[10];
  const float* b1   = (const float*)d_in[11];
  const float* w2   = (const float*)d_in[12];
  const float* b2   = (const float*)d_in[13];
  const float* alng = (const float*)d_in[14];
  const float* alnb = (const float*)d_in[15];
  const float* wd   = (const float*)d_in[16];
  const float* bd   = (const float*)d_in[17];
  const float* wu   = (const float*)d_in[18];
  const float* bu   = (const float*)d_in[19];
  float* out = (float*)d_out;

  char* W = (char*)d_ws;
  size_t off = 0;
  auto allocB = [&](size_t bytes) { void* p = W + off; off += (bytes + 255) & ~(size_t)255; return p; };
  const size_t T = 8192;
  unsigned short* wqkvt = (unsigned short*)allocB((size_t)3072 * 1024 * 2);  // [3072][1024]
  unsigned short* wot   = (unsigned short*)allocB((size_t)1024 * 1024 * 2);
  unsigned short* w1t   = (unsigned short*)allocB((size_t)4096 * 1024 * 2);
  unsigned short* w2t   = (unsigned short*)allocB((size_t)4096 * 1024 * 2);
  unsigned short* wdt   = (unsigned short*)allocB(64 * 1024 * 2);
  unsigned short* wut   = (unsigned short*)allocB(64 * 1024 * 2);
  unsigned short* H     = (unsigned short*)allocB(T * 1024 * 2);
  unsigned short* QKV   = (unsigned short*)allocB(T * 3072 * 2);   // [8192][3072]
  unsigned short* VT    = (unsigned short*)allocB(T * 1024 * 2);
  float* X2             = (float*)allocB(T * 1024 * 4);
  unsigned short* MID   = (unsigned short*)allocB(T * 4096 * 2);
  // overlays (buffers dead by the time overlay is written):
  unsigned short* AO  = MID;          // attn out [8192][1024], dead before FFN1 writes MID
  unsigned short* DWN = VT;           // adapter-down out, VT dead after attn
  float* ADP          = (float*)QKV;  // adapter-up out fp32 32MB in QKV (48MB), dead after attn
  if (ws_size < off) return;

  dim3 blk(256);
  transpose_cvt_k<<<dim3(32, 32), blk, 0, stream>>>(wq, wqkvt, 1024, 1024);
  transpose_cvt_k<<<dim3(32, 32), blk, 0, stream>>>(wk, wqkvt + (size_t)1024 * 1024, 1024, 1024);
  transpose_cvt_k<<<dim3(32, 32), blk, 0, stream>>>(wv, wqkvt + (size_t)2048 * 1024, 1024, 1024);
  transpose_cvt_k<<<dim3(32, 32), blk, 0, stream>>>(wo, wot, 1024, 1024);
  transpose_cvt_k<<<dim3(128, 32), blk, 0, stream>>>(w1, w1t, 1024, 4096);
  transpose_cvt_k<<<dim3(32, 128), blk, 0, stream>>>(w2, w2t, 4096, 1024);
  transpose_cvt_k<<<dim3(2, 32), blk, 0, stream>>>(wd, wdt, 1024, 64);
  transpose_cvt_k<<<dim3(32, 2), blk, 0, stream>>>(wu, wut, 64, 1024);

  ln_k<<<8192, blk, 0, stream>>>(x, ln1g, ln1b, H);
  // QKV fused: [8192,1024] x [3072,1024]^T -> [8192,3072]
  gemm8_k<128, 256, EPI_NONE, unsigned short><<<768, 512, 0, stream>>>(
      H, wqkvt, QKV, nullptr, nullptr, nullptr, 8192, 3072, 1024, 64, 12);
  vtrans_k<<<dim3(32, 2, 128), blk, 0, stream>>>(QKV + 2048, VT, 3072);
  attn_k<<<dim3(16, 128), blk, 0, stream>>>(QKV, QKV + 1024, VT, AO, 3072);
  gemm8_k<128, 256, EPI_BIAS_RES, float><<<256, 512, 0, stream>>>(
      AO, wot, X2, bo, x, nullptr, 8192, 1024, 1024, 64, 4);
  ln_k<<<8192, blk, 0, stream>>>(X2, alng, alnb, H);
  gemm_k<64, EPI_RELU, unsigned short><<<dim3(64, 1), blk, 0, stream>>>(
      H, wdt, DWN, bd, nullptr, nullptr, 8192, 64, 1024);
  gemm_k<128, EPI_SCALE_BIAS, float><<<dim3(64, 8), blk, 0, stream>>>(
      DWN, wut, ADP, bu, nullptr, nullptr, 8192, 1024, 64);
  ln_k<<<8192, blk, 0, stream>>>(X2, ln2g, ln2b, H);
  gemm8_k<256, 256, EPI_GELU, unsigned short><<<512, 512, 0, stream>>>(
      H, w1t, MID, b1, nullptr, nullptr, 8192, 4096, 1024, 32, 16);
  gemm8_k<128, 256, EPI_FINAL, float><<<256, 512, 0, stream>>>(
      MID, w2t, out, b2, X2, ADP, 8192, 1024, 4096, 64, 4);
}

// Round 4
// 570.425 us; speedup vs baseline: 1.1593x; 1.0754x over previous
//
#include <hip/hip_runtime.h>
#include <hip/hip_bf16.h>
#include <cstdint>
#include <cstddef>

#define DI __device__ __forceinline__

typedef __attribute__((ext_vector_type(8))) short v8s;
typedef __attribute__((ext_vector_type(4))) float v4f;
typedef __attribute__((ext_vector_type(16))) float v16f;

DI void gload_lds16(const unsigned short* g, unsigned short* l) {
  __builtin_amdgcn_global_load_lds(
      (const __attribute__((address_space(1))) unsigned int*)g,
      (__attribute__((address_space(3))) unsigned int*)l, 16, 0, 0);
}

DI float bf2f(unsigned short u) { return __uint_as_float(((unsigned int)u) << 16); }
DI unsigned short f2bf(float f) {
  unsigned int u = __float_as_uint(f);
  u += 0x7FFFu + ((u >> 16) & 1u);
  return (unsigned short)(u >> 16);
}

// ------------- transpose+convert: in[R][C] fp32 -> out[C][R] bf16 -------------
__global__ __launch_bounds__(256) void transpose_cvt_k(
    const float* __restrict__ in, unsigned short* __restrict__ out, int R, int C) {
  __shared__ unsigned short t[32][33];
  const int j0 = blockIdx.x * 32, i0 = blockIdx.y * 32;
  const int tx = threadIdx.x & 31, ty = threadIdx.x >> 5;
#pragma unroll
  for (int r = 0; r < 32; r += 8) t[ty + r][tx] = f2bf(in[(size_t)(i0 + ty + r) * C + j0 + tx]);
  __syncthreads();
#pragma unroll
  for (int r = 0; r < 32; r += 8) out[(size_t)(j0 + ty + r) * R + i0 + tx] = t[tx][ty + r];
}

// V region [T=8192, ld] bf16 -> VT [B*H][64 d][1024 s] bf16
__global__ __launch_bounds__(256) void vtrans_k(
    const unsigned short* __restrict__ v, unsigned short* __restrict__ vt, int ld) {
  __shared__ unsigned short t[32][33];
  const int bh = blockIdx.z, b = bh >> 4, h = bh & 15;
  const int s0 = blockIdx.x * 32, d0 = blockIdx.y * 32;
  const int tx = threadIdx.x & 31, ty = threadIdx.x >> 5;
  const unsigned short* src = v + (size_t)(b * 1024 + s0) * ld + h * 64 + d0;
#pragma unroll
  for (int r = 0; r < 32; r += 8) t[ty + r][tx] = src[(size_t)(ty + r) * ld + tx];
  __syncthreads();
  unsigned short* dst = vt + ((size_t)bh * 64 + d0) * 1024 + s0;
#pragma unroll
  for (int r = 0; r < 32; r += 8) dst[(size_t)(ty + r) * 1024 + tx] = t[tx][ty + r];
}

// ------------- LayerNorm: fp32 in, bf16 out, D=1024 -------------
__global__ __launch_bounds__(256) void ln_k(
    const float* __restrict__ x, const float* __restrict__ g,
    const float* __restrict__ b, unsigned short* __restrict__ out) {
  const int row = blockIdx.x;
  const float4 v = ((const float4*)(x + (size_t)row * 1024))[threadIdx.x];
  float s = v.x + v.y + v.z + v.w;
  float ss = v.x * v.x + v.y * v.y + v.z * v.z + v.w * v.w;
#pragma unroll
  for (int o = 1; o < 64; o <<= 1) { s += __shfl_xor(s, o); ss += __shfl_xor(ss, o); }
  __shared__ float red[8];
  const int wid = threadIdx.x >> 6, lane = threadIdx.x & 63;
  if (!lane) { red[wid] = s; red[4 + wid] = ss; }
  __syncthreads();
  s = red[0] + red[1] + red[2] + red[3];
  ss = red[4] + red[5] + red[6] + red[7];
  const float mean = s * (1.f / 1024.f);
  const float var = ss * (1.f / 1024.f) - mean * mean;
  const float rs = rsqrtf(var + 1e-5f);
  const float4 gv = ((const float4*)g)[threadIdx.x];
  const float4 bv = ((const float4*)b)[threadIdx.x];
  ushort4 ov;
  ov.x = f2bf((v.x - mean) * rs * gv.x + bv.x);
  ov.y = f2bf((v.y - mean) * rs * gv.y + bv.y);
  ov.z = f2bf((v.z - mean) * rs * gv.z + bv.z);
  ov.w = f2bf((v.w - mean) * rs * gv.w + bv.w);
  ((ushort4*)(out + (size_t)row * 1024))[threadIdx.x] = ov;
}

// dual-output LN: one X2 read, two (g,b) sets, two bf16 outputs
__global__ __launch_bounds__(256) void ln_dual_k(
    const float* __restrict__ x, const float* __restrict__ g1, const float* __restrict__ b1,
    const float* __restrict__ g2, const float* __restrict__ b2,
    unsigned short* __restrict__ o1, unsigned short* __restrict__ o2) {
  const int row = blockIdx.x;
  const float4 v = ((const float4*)(x + (size_t)row * 1024))[threadIdx.x];
  float s = v.x + v.y + v.z + v.w;
  float ss = v.x * v.x + v.y * v.y + v.z * v.z + v.w * v.w;
#pragma unroll
  for (int o = 1; o < 64; o <<= 1) { s += __shfl_xor(s, o); ss += __shfl_xor(ss, o); }
  __shared__ float red[8];
  const int wid = threadIdx.x >> 6, lane = threadIdx.x & 63;
  if (!lane) { red[wid] = s; red[4 + wid] = ss; }
  __syncthreads();
  s = red[0] + red[1] + red[2] + red[3];
  ss = red[4] + red[5] + red[6] + red[7];
  const float mean = s * (1.f / 1024.f);
  const float var = ss * (1.f / 1024.f) - mean * mean;
  const float rs = rsqrtf(var + 1e-5f);
  const float n0 = (v.x - mean) * rs, n1 = (v.y - mean) * rs, n2 = (v.z - mean) * rs, n3 = (v.w - mean) * rs;
  {
    const float4 gv = ((const float4*)g1)[threadIdx.x];
    const float4 bv = ((const float4*)b1)[threadIdx.x];
    ushort4 ov{f2bf(n0 * gv.x + bv.x), f2bf(n1 * gv.y + bv.y), f2bf(n2 * gv.z + bv.z), f2bf(n3 * gv.w + bv.w)};
    ((ushort4*)(o1 + (size_t)row * 1024))[threadIdx.x] = ov;
  }
  {
    const float4 gv = ((const float4*)g2)[threadIdx.x];
    const float4 bv = ((const float4*)b2)[threadIdx.x];
    ushort4 ov{f2bf(n0 * gv.x + bv.x), f2bf(n1 * gv.y + bv.y), f2bf(n2 * gv.z + bv.z), f2bf(n3 * gv.w + bv.w)};
    ((ushort4*)(o2 + (size_t)row * 1024))[threadIdx.x] = ov;
  }
}

enum { EPI_NONE = 0, EPI_BIAS_RES = 1, EPI_GELU = 2, EPI_RELU = 3, EPI_SCALE_BIAS = 4, EPI_FINAL = 5 };

// ======= 8-wave pipelined GEMM; PH phases/K-tile so every shape gets 16 MFMA/phase =======
template <int BM, int BN, int EPI, typename CT>
__global__ __launch_bounds__(512, 2) void gemm8_k(
    const unsigned short* __restrict__ A, const unsigned short* __restrict__ Bt,
    CT* __restrict__ C, const float* __restrict__ bias,
    const float* __restrict__ res, const float* __restrict__ extra,
    int M, int N, int K, int gm, int gn) {
  constexpr int MF = BM / 32, NF = BN / 64;
  constexpr int PH = (MF * NF) / 8 < 1 ? 1 : (MF * NF) / 8;  // 16 MFMA per phase
  constexpr int MPP = MF / PH;
  constexpr int LA = BM / 64, LB = BN / 64, LT = LA + LB;
  constexpr int BUFE = (BM + BN) * 64;
  __shared__ unsigned short lds[BUFE * 2];
  const int tid = threadIdx.x;
  const int lane = tid & 63, wid = tid >> 6;
  const int wm = wid >> 2, wn = wid & 3;
  const int l15 = lane & 15, l4 = lane >> 4;
  const int nwg = gm * gn;
  const int bid = blockIdx.x;
  const int swz = (bid % 8) * (nwg / 8) + bid / 8;  // XCD swizzle (nwg % 8 == 0)
  const int row0 = (swz / gn) * BM, col0 = (swz % gn) * BN;
  const int NT = K >> 6;

  const int srow = tid >> 3, sgr = tid & 7;
  auto stA = [&](int kt, int b, int a) {
    const unsigned short* s = A + (size_t)(row0 + a * 64 + srow) * K + kt * 64 + ((sgr ^ (srow & 7)) << 3);
    gload_lds16(s, lds + b * BUFE + a * 4096 + tid * 8);
  };
  auto stB = [&](int kt, int b, int a) {
    const unsigned short* s = Bt + (size_t)(col0 + a * 64 + srow) * K + kt * 64 + ((sgr ^ (srow & 7)) << 3);
    gload_lds16(s, lds + b * BUFE + BM * 64 + a * 4096 + tid * 8);
  };

#pragma unroll
  for (int e = 0; e < LA; ++e) stA(0, 0, e);
#pragma unroll
  for (int e = 0; e < LB; ++e) stB(0, 0, e);
  if (NT > 1) {
#pragma unroll
    for (int e = 0; e < LB; ++e) stB(1, 1, e);
    asm volatile("s_waitcnt vmcnt(%0)" ::"n"(LB) : "memory");
  } else {
    asm volatile("s_waitcnt vmcnt(0)" ::: "memory");
  }
  __builtin_amdgcn_s_barrier();

  v4f acc[MF][NF] = {};
  v8s bfr[NF][2];
  for (int t = 0; t < NT; ++t) {
    const int buf = t & 1;
    const unsigned short* La = lds + buf * BUFE;
    const unsigned short* Lb = lds + buf * BUFE + BM * 64;
#pragma unroll
    for (int p = 0; p < PH; ++p) {
      if (p == 0) {
#pragma unroll
        for (int nf = 0; nf < NF; ++nf) {
          const int r = wn * (BN / 4) + nf * 16 + l15;
#pragma unroll
          for (int kk = 0; kk < 2; ++kk)
            bfr[nf][kk] = *(const v8s*)(Lb + r * 64 + ((kk * 32 + l4 * 8) ^ ((r & 7) << 3)));
        }
      }
      v8s af[MPP][2];
#pragma unroll
      for (int mm = 0; mm < MPP; ++mm) {
        const int r = wm * (BM / 2) + (p * MPP + mm) * 16 + l15;
#pragma unroll
        for (int kk = 0; kk < 2; ++kk)
          af[mm][kk] = *(const v8s*)(La + r * 64 + ((kk * 32 + l4 * 8) ^ ((r & 7) << 3)));
      }
#pragma unroll
      for (int e = p * LT / PH; e < (p + 1) * LT / PH; ++e) {
        if (e < LA) { if (t + 1 < NT) stA(t + 1, buf ^ 1, e); }
        else        { if (t + 2 < NT) stB(t + 2, buf, e - LA); }
      }
      __builtin_amdgcn_s_barrier();
      asm volatile("s_waitcnt lgkmcnt(0)" ::: "memory");
      __builtin_amdgcn_s_setprio(1);
#pragma unroll
      for (int mm = 0; mm < MPP; ++mm)
#pragma unroll
        for (int nf = 0; nf < NF; ++nf)
#pragma unroll
          for (int kk = 0; kk < 2; ++kk)
            acc[p * MPP + mm][nf] = __builtin_amdgcn_mfma_f32_16x16x32_bf16(
                af[mm][kk], bfr[nf][kk], acc[p * MPP + mm][nf], 0, 0, 0);
      __builtin_amdgcn_s_setprio(0);
      if (p == PH - 1 && t + 1 < NT) {
        if (t + 2 < NT) asm volatile("s_waitcnt vmcnt(%0)" ::"n"(LB) : "memory");
        else            asm volatile("s_waitcnt vmcnt(0)" ::: "memory");
      }
      __builtin_amdgcn_s_barrier();
    }
  }

#pragma unroll
  for (int mf = 0; mf < MF; ++mf) {
#pragma unroll
    for (int nf = 0; nf < NF; ++nf) {
      const int col = col0 + wn * (BN / 4) + nf * 16 + l15;
      float bv = 0.f;
      if (EPI != EPI_NONE) bv = bias[col];
#pragma unroll
      for (int j = 0; j < 4; ++j) {
        const int row = row0 + wm * (BM / 2) + mf * 16 + l4 * 4 + j;
        const size_t idx = (size_t)row * N + col;
        float v = acc[mf][nf][j];
        if (EPI == EPI_BIAS_RES) v += bv + res[idx];
        else if (EPI == EPI_GELU) { v += bv; v = 0.5f * v * (1.f + erff(v * 0.70710678118f)); }
        else if (EPI == EPI_RELU) { v += bv; v = fmaxf(v, 0.f); }
        else if (EPI == EPI_SCALE_BIAS) { v = (v + bv) * 0.1f; }
        else if (EPI == EPI_FINAL) { v += bv + res[idx] + extra[idx]; }
        if constexpr (sizeof(CT) == 2) C[idx] = f2bf(v); else C[idx] = v;
      }
    }
  }
}

// ------------- small 2-phase GEMM (adapters: N=64 / K=64) -------------
template <int BN, int EPI, typename CT>
__global__ __launch_bounds__(256) void gemm_k(
    const unsigned short* __restrict__ A, const unsigned short* __restrict__ Bt,
    CT* __restrict__ C, const float* __restrict__ bias,
    const float* __restrict__ res, const float* __restrict__ extra,
    int M, int N, int K) {
  constexpr int BM = 128, BK = 32;
  constexpr int WN = (BN == 128) ? 2 : 1;
  constexpr int MR = (BN == 128) ? 4 : 2;
  constexpr int NR = 4;
  __shared__ unsigned short sA[BM * BK];
  __shared__ unsigned short sB[BN * BK];
  const int tid = threadIdx.x;
  const int lane = tid & 63, wid = tid >> 6;
  const int wm = wid / WN, wn = wid % WN;
  const int l15 = lane & 15, l4 = lane >> 4;
  const int row0 = blockIdx.x * BM, col0 = blockIdx.y * BN;
  v4f acc[MR][NR] = {};
  const int rowA = wm * MR * 16;
  const int rowB = wn * NR * 16;
  for (int k0 = 0; k0 < K; k0 += BK) {
#pragma unroll
    for (int r = 0; r < (BM * BK) / (256 * 8); ++r) {
      int e = (r * 256 + tid) * 8;
      gload_lds16(A + (size_t)(row0 + (e >> 5)) * K + k0 + (e & 31), ((unsigned short*)sA) + e);
    }
#pragma unroll
    for (int r = 0; r < (BN * BK) / (256 * 8); ++r) {
      int e = (r * 256 + tid) * 8;
      gload_lds16(Bt + (size_t)(col0 + (e >> 5)) * K + k0 + (e & 31), ((unsigned short*)sB) + e);
    }
    __syncthreads();
    v8s af[MR], bfr2[NR];
#pragma unroll
    for (int m = 0; m < MR; ++m) af[m] = *(const v8s*)(sA + (rowA + m * 16 + l15) * BK + l4 * 8);
#pragma unroll
    for (int n = 0; n < NR; ++n) bfr2[n] = *(const v8s*)(sB + (rowB + n * 16 + l15) * BK + l4 * 8);
#pragma unroll
    for (int m = 0; m < MR; ++m)
#pragma unroll
      for (int n = 0; n < NR; ++n)
        acc[m][n] = __builtin_amdgcn_mfma_f32_16x16x32_bf16(af[m], bfr2[n], acc[m][n], 0, 0, 0);
    __syncthreads();
  }
#pragma unroll
  for (int m = 0; m < MR; ++m) {
#pragma unroll
    for (int n = 0; n < NR; ++n) {
      const int col = col0 + rowB + n * 16 + l15;
      float bv = 0.f;
      if (EPI != EPI_NONE) bv = bias[col];
#pragma unroll
      for (int j = 0; j < 4; ++j) {
        const int row = row0 + rowA + m * 16 + l4 * 4 + j;
        const size_t idx = (size_t)row * N + col;
        float v = acc[m][n][j];
        if (EPI == EPI_BIAS_RES) v += bv + res[idx];
        else if (EPI == EPI_GELU) { v += bv; v = 0.5f * v * (1.f + erff(v * 0.70710678118f)); }
        else if (EPI == EPI_RELU) { v += bv; v = fmaxf(v, 0.f); }
        else if (EPI == EPI_SCALE_BIAS) { v = (v + bv) * 0.1f; }
        else if (EPI == EPI_FINAL) { v += bv + res[idx] + extra[idx]; }
        if constexpr (sizeof(CT) == 2) C[idx] = f2bf(v); else C[idx] = v;
      }
    }
  }
}

// ======= flash attention: 4 waves x 32 q-rows, KVBLK=64, mfma 32x32x16, in-reg softmax =======
// Q from QKV (ld 3072), K from QKV+1024, V^T from VT [bh][64][1024]. Out: O [8192][1024].
__global__ __launch_bounds__(256) void attn_k(
    const unsigned short* __restrict__ QKV, const unsigned short* __restrict__ VT,
    unsigned short* __restrict__ O) {
  const int bid = blockIdx.x;
  const int swz = (bid & 7) * 128 + (bid >> 3);  // XCD-local: one XCD owns 16 bh
  const int bh = swz >> 3, qb = swz & 7;
  const int b = bh >> 4, h = bh & 15;
  const int tid = threadIdx.x, lane = tid & 63, w = tid >> 6;
  const int l31 = lane & 31, hi = lane >> 5;
  __shared__ unsigned short sK[2][64 * 64];
  __shared__ unsigned short sV[2][64 * 64];
  const int q0 = qb * 128;
  // Q fragments in registers (B-operand: col=q, k-chunks of d)
  const unsigned short* Qrow = QKV + (size_t)(b * 1024 + q0 + w * 32 + l31) * 3072 + h * 64;
  v8s qf[4];
#pragma unroll
  for (int kcd = 0; kcd < 4; ++kcd) qf[kcd] = *(const v8s*)(Qrow + kcd * 16 + hi * 8);

  const unsigned short* Kbase = QKV + 1024 + (size_t)(b * 1024) * 3072 + h * 64;
  const unsigned short* Vbase = VT + (size_t)bh * 64 * 1024;
  const int sr = tid >> 3, sg = tid & 7;
  auto stage = [&](int t, int bsel) {
    const int k0 = t * 64;
#pragma unroll
    for (int ps = 0; ps < 2; ++ps) {
      const int r = ps * 32 + sr;
      gload_lds16(Kbase + (size_t)(k0 + r) * 3072 + ((sg ^ (r & 7)) << 3), &sK[bsel][r * 64 + sg * 8]);
    }
#pragma unroll
    for (int ps = 0; ps < 2; ++ps) {
      const int r = ps * 32 + sr;
      gload_lds16(Vbase + (size_t)r * 1024 + k0 + ((sg ^ (r & 7)) << 3), &sV[bsel][r * 64 + sg * 8]);
    }
  };
  stage(0, 0);
  asm volatile("s_waitcnt vmcnt(0)" ::: "memory");
  __syncthreads();

  const float SC = 0.125f * 1.44269504f;  // scale * log2(e): softmax in exp2 domain
  float m_run = -3e38f, l_run = 0.f;
  v16f oacc0 = {}, oacc1 = {};

  for (int t = 0; t < 16; ++t) {
    const int cur = t & 1;
    if (t + 1 < 16) stage(t + 1, cur ^ 1);  // issue early (T14)
    // ---- QK^T: S^T[key][q], key-subtiles 0/1 ----
    v16f s0 = {}, s1 = {};
#pragma unroll
    for (int kcd = 0; kcd < 4; ++kcd) {
      const int c = kcd * 2 + hi;
      v8s a0 = *(const v8s*)(&sK[cur][l31 * 64 + ((c ^ (l31 & 7)) << 3)]);
      v8s a1 = *(const v8s*)(&sK[cur][(32 + l31) * 64 + ((c ^ (l31 & 7)) << 3)]);
      s0 = __builtin_amdgcn_mfma_f32_32x32x16_bf16(a0, qf[kcd], s0, 0, 0, 0);
      s1 = __builtin_amdgcn_mfma_f32_32x32x16_bf16(a1, qf[kcd], s1, 0, 0, 0);
    }
    // ---- softmax (lane-local row, partner lane^32 has other key-half) ----
    float p0[16], p1[16];
#pragma unroll
    for (int i = 0; i < 16; ++i) { p0[i] = s0[i] * SC; p1[i] = s1[i] * SC; }
    float mx = fmaxf(p0[0], p1[0]);
#pragma unroll
    for (int i = 1; i < 16; ++i) mx = fmaxf(mx, fmaxf(p0[i], p1[i]));
    mx = fmaxf(mx, __shfl_xor(mx, 32));
    const float m_new = fmaxf(m_run, mx);
    const float fac = exp2f(m_run - m_new);
    float ts = 0.f;
#pragma unroll
    for (int i = 0; i < 16; ++i) {
      p0[i] = exp2f(p0[i] - m_new);
      p1[i] = exp2f(p1[i] - m_new);
      ts += p0[i] + p1[i];
    }
    ts += __shfl_xor(ts, 32);
    l_run = l_run * fac + ts;
    m_run = m_new;
#pragma unroll
    for (int i = 0; i < 16; ++i) { oacc0[i] *= fac; oacc1[i] *= fac; }
    // ---- P^T -> bf16 B-frags via cvt_pk + permlane32_swap ----
    auto mkfrag = [&](const float* p, int c) -> v8s {
      unsigned A0, A1, A2, A3;
      asm("v_cvt_pk_bf16_f32 %0, %1, %2" : "=v"(A0) : "v"(p[8 * c + 0]), "v"(p[8 * c + 1]));
      asm("v_cvt_pk_bf16_f32 %0, %1, %2" : "=v"(A1) : "v"(p[8 * c + 2]), "v"(p[8 * c + 3]));
      asm("v_cvt_pk_bf16_f32 %0, %1, %2" : "=v"(A2) : "v"(p[8 * c + 4]), "v"(p[8 * c + 5]));
      asm("v_cvt_pk_bf16_f32 %0, %1, %2" : "=v"(A3) : "v"(p[8 * c + 6]), "v"(p[8 * c + 7]));
      asm("v_permlane32_swap_b32 %0, %1" : "+v"(A2), "+v"(A0));
      asm("v_permlane32_swap_b32 %0, %1" : "+v"(A3), "+v"(A1));
      union { unsigned u[4]; v8s v; } r;
      r.u[0] = A0; r.u[1] = A1; r.u[2] = A2; r.u[3] = A3;
      return r.v;
    };
    v8s pB0 = mkfrag(p0, 0), pB1 = mkfrag(p0, 1), pB2 = mkfrag(p1, 0), pB3 = mkfrag(p1, 1);
    // ---- PV: O^T[d][q] += V^T . P^T ----
#pragma unroll
    for (int kc = 0; kc < 4; ++kc) {
      const v8s pb = (kc == 0) ? pB0 : (kc == 1) ? pB1 : (kc == 2) ? pB2 : pB3;
      const int c = kc * 2 + hi;
      v8s vf0 = *(const v8s*)(&sV[cur][l31 * 64 + ((c ^ (l31 & 7)) << 3)]);
      v8s vf1 = *(const v8s*)(&sV[cur][(32 + l31) * 64 + ((c ^ (l31 & 7)) << 3)]);
      oacc0 = __builtin_amdgcn_mfma_f32_32x32x16_bf16(vf0, pb, oacc0, 0, 0, 0);
      oacc1 = __builtin_amdgcn_mfma_f32_32x32x16_bf16(vf1, pb, oacc1, 0, 0, 0);
    }
    if (t + 1 < 16) {
      asm volatile("s_waitcnt vmcnt(0)" ::: "memory");  // next tile landed
      __syncthreads();                                  // all waves done reading cur
    }
  }
  // ---- store O[q][d] (row fixed per lane; 8B chunks) ----
  const float inv = 1.f / l_run;
  unsigned short* Orow = O + (size_t)(b * 1024 + q0 + w * 32 + l31) * 1024 + h * 64;
#pragma unroll
  for (int g = 0; g < 4; ++g) {
    ushort4 st0{f2bf(oacc0[4 * g + 0] * inv), f2bf(oacc0[4 * g + 1] * inv),
                f2bf(oacc0[4 * g + 2] * inv), f2bf(oacc0[4 * g + 3] * inv)};
    ushort4 st1{f2bf(oacc1[4 * g + 0] * inv), f2bf(oacc1[4 * g + 1] * inv),
                f2bf(oacc1[4 * g + 2] * inv), f2bf(oacc1[4 * g + 3] * inv)};
    *(ushort4*)(Orow + g * 8 + hi * 4) = st0;
    *(ushort4*)(Orow + 32 + g * 8 + hi * 4) = st1;
  }
}

// ---------------- launch ----------------
extern "C" void kernel_launch(void* const* d_in, const int* in_sizes, int n_in,
                              void* d_out, int out_size, void* d_ws, size_t ws_size,
                              hipStream_t stream) {
  (void)in_sizes; (void)n_in; (void)out_size;
  const float* x    = (const float*)d_in[0];
  const float* ln1g = (const float*)d_in[1];
  const float* ln1b = (const float*)d_in[2];
  const float* wq   = (const float*)d_in[3];
  const float* wk   = (const float*)d_in[4];
  const float* wv   = (const float*)d_in[5];
  const float* wo   = (const float*)d_in[6];
  const float* bo   = (const float*)d_in[7];
  const float* ln2g = (const float*)d_in[8];
  const float* ln2b = (const float*)d_in[9];
  const float* w1   = (const float*)d_in[10];
  const float* b1   = (const float*)d_in[11];
  const float* w2   = (const float*)d_in[12];
  const float* b2   = (const float*)d_in[13];
  const float* alng = (const float*)d_in[14];
  const float* alnb = (const float*)d_in[15];
  const float* wd   = (const float*)d_in[16];
  const float* bd   = (const float*)d_in[17];
  const float* wu   = (const float*)d_in[18];
  const float* bu   = (const float*)d_in[19];
  float* out = (float*)d_out;

  char* W = (char*)d_ws;
  size_t off = 0;
  auto allocB = [&](size_t bytes) { void* p = W + off; off += (bytes + 255) & ~(size_t)255; return p; };
  const size_t T = 8192;
  unsigned short* wqkvt = (unsigned short*)allocB((size_t)3072 * 1024 * 2);
  unsigned short* wot   = (unsigned short*)allocB((size_t)1024 * 1024 * 2);
  unsigned short* w1t   = (unsigned short*)allocB((size_t)4096 * 1024 * 2);
  unsigned short* w2t   = (unsigned short*)allocB((size_t)4096 * 1024 * 2);
  unsigned short* wdt   = (unsigned short*)allocB(64 * 1024 * 2);
  unsigned short* wut   = (unsigned short*)allocB(64 * 1024 * 2);
  unsigned short* H     = (unsigned short*)allocB(T * 1024 * 2);
  unsigned short* H2    = (unsigned short*)allocB(T * 1024 * 2);
  unsigned short* QKV   = (unsigned short*)allocB(T * 3072 * 2);
  unsigned short* VT    = (unsigned short*)allocB(T * 1024 * 2);
  float* X2             = (float*)allocB(T * 1024 * 4);
  unsigned short* MID   = (unsigned short*)allocB(T * 4096 * 2);
  // overlays (dead buffers):
  unsigned short* AO  = MID;          // attn out, dead before FFN1 writes MID
  unsigned short* DWN = VT;           // adapter-down out, VT dead after attn
  float* ADP          = (float*)QKV;  // adapter-up out fp32 (32MB in 48MB), QKV dead after attn
  if (ws_size < off) return;

  dim3 blk(256);
  transpose_cvt_k<<<dim3(32, 32), blk, 0, stream>>>(wq, wqkvt, 1024, 1024);
  transpose_cvt_k<<<dim3(32, 32), blk, 0, stream>>>(wk, wqkvt + (size_t)1024 * 1024, 1024, 1024);
  transpose_cvt_k<<<dim3(32, 32), blk, 0, stream>>>(wv, wqkvt + (size_t)2048 * 1024, 1024, 1024);
  transpose_cvt_k<<<dim3(32, 32), blk, 0, stream>>>(wo, wot, 1024, 1024);
  transpose_cvt_k<<<dim3(128, 32), blk, 0, stream>>>(w1, w1t, 1024, 4096);
  transpose_cvt_k<<<dim3(32, 128), blk, 0, stream>>>(w2, w2t, 4096, 1024);
  transpose_cvt_k<<<dim3(2, 32), blk, 0, stream>>>(wd, wdt, 1024, 64);
  transpose_cvt_k<<<dim3(32, 2), blk, 0, stream>>>(wu, wut, 64, 1024);

  ln_k<<<8192, blk, 0, stream>>>(x, ln1g, ln1b, H);
  gemm8_k<128, 256, EPI_NONE, unsigned short><<<768, 512, 0, stream>>>(
      H, wqkvt, QKV, nullptr, nullptr, nullptr, 8192, 3072, 1024, 64, 12);
  vtrans_k<<<dim3(32, 2, 128), blk, 0, stream>>>(QKV + 2048, VT, 3072);
  attn_k<<<1024, blk, 0, stream>>>(QKV, VT, AO);
  gemm8_k<128, 256, EPI_BIAS_RES, float><<<256, 512, 0, stream>>>(
      AO, wot, X2, bo, x, nullptr, 8192, 1024, 1024, 64, 4);
  ln_dual_k<<<8192, blk, 0, stream>>>(X2, alng, alnb, ln2g, ln2b, H, H2);
  gemm_k<64, EPI_RELU, unsigned short><<<dim3(64, 1), blk, 0, stream>>>(
      H, wdt, DWN, bd, nullptr, nullptr, 8192, 64, 1024);
  gemm_k<128, EPI_SCALE_BIAS, float><<<dim3(64, 8), blk, 0, stream>>>(
      DWN, wut, ADP, bu, nullptr, nullptr, 8192, 1024, 64);
  gemm8_k<256, 256, EPI_GELU, unsigned short><<<512, 512, 0, stream>>>(
      H2, w1t, MID, b1, nullptr, nullptr, 8192, 4096, 1024, 32, 16);
  gemm8_k<128, 256, EPI_FINAL, float><<<256, 512, 0, stream>>>(
      MID, w2t, out, b2, X2, ADP, 8192, 1024, 4096, 64, 4);
}

// Round 6
// 550.319 us; speedup vs baseline: 1.2017x; 1.0365x over previous
//
#include <hip/hip_runtime.h>
#include <hip/hip_bf16.h>
#include <cstdint>
#include <cstddef>

#define DI __device__ __forceinline__

typedef __attribute__((ext_vector_type(8))) short v8s;
typedef __attribute__((ext_vector_type(4))) float v4f;
typedef __attribute__((ext_vector_type(16))) float v16f;

DI void gload_lds16(const unsigned short* g, unsigned short* l) {
  __builtin_amdgcn_global_load_lds(
      (const __attribute__((address_space(1))) unsigned int*)g,
      (__attribute__((address_space(3))) unsigned int*)l, 16, 0, 0);
}

DI float bf2f(unsigned short u) { return __uint_as_float(((unsigned int)u) << 16); }
DI unsigned short f2bf(float f) {
  unsigned int u = __float_as_uint(f);
  u += 0x7FFFu + ((u >> 16) & 1u);
  return (unsigned short)(u >> 16);
}

// Abramowitz-Stegun 7.1.26, |eps| <= 1.5e-7
DI float fast_erf(float x) {
  const float ax = fabsf(x);
  const float t = __builtin_amdgcn_rcpf(1.f + 0.3275911f * ax);
  const float y = t * (0.254829592f + t * (-0.284496736f + t * (1.421413741f +
                   t * (-1.453152027f + t * 1.061405429f))));
  const float r = 1.f - y * __expf(-ax * ax);
  return copysignf(r, x);
}

// ------------- transpose+convert: in[R][C] fp32 -> out[C][R] bf16 -------------
__global__ __launch_bounds__(256) void transpose_cvt_k(
    const float* __restrict__ in, unsigned short* __restrict__ out, int R, int C) {
  __shared__ unsigned short t[32][33];
  const int j0 = blockIdx.x * 32, i0 = blockIdx.y * 32;
  const int tx = threadIdx.x & 31, ty = threadIdx.x >> 5;
#pragma unroll
  for (int r = 0; r < 32; r += 8) t[ty + r][tx] = f2bf(in[(size_t)(i0 + ty + r) * C + j0 + tx]);
  __syncthreads();
#pragma unroll
  for (int r = 0; r < 32; r += 8) out[(size_t)(j0 + ty + r) * R + i0 + tx] = t[tx][ty + r];
}

// V region [T=8192, ld] bf16 -> VT [B*H][64 d][1024 s] bf16
__global__ __launch_bounds__(256) void vtrans_k(
    const unsigned short* __restrict__ v, unsigned short* __restrict__ vt, int ld) {
  __shared__ unsigned short t[32][33];
  const int bh = blockIdx.z, b = bh >> 4, h = bh & 15;
  const int s0 = blockIdx.x * 32, d0 = blockIdx.y * 32;
  const int tx = threadIdx.x & 31, ty = threadIdx.x >> 5;
  const unsigned short* src = v + (size_t)(b * 1024 + s0) * ld + h * 64 + d0;
#pragma unroll
  for (int r = 0; r < 32; r += 8) t[ty + r][tx] = src[(size_t)(ty + r) * ld + tx];
  __syncthreads();
  unsigned short* dst = vt + ((size_t)bh * 64 + d0) * 1024 + s0;
#pragma unroll
  for (int r = 0; r < 32; r += 8) dst[(size_t)(ty + r) * 1024 + tx] = t[tx][ty + r];
}

// ------------- LayerNorm: fp32 in, bf16 out, D=1024 -------------
__global__ __launch_bounds__(256) void ln_k(
    const float* __restrict__ x, const float* __restrict__ g,
    const float* __restrict__ b, unsigned short* __restrict__ out) {
  const int row = blockIdx.x;
  const float4 v = ((const float4*)(x + (size_t)row * 1024))[threadIdx.x];
  float s = v.x + v.y + v.z + v.w;
  float ss = v.x * v.x + v.y * v.y + v.z * v.z + v.w * v.w;
#pragma unroll
  for (int o = 1; o < 64; o <<= 1) { s += __shfl_xor(s, o); ss += __shfl_xor(ss, o); }
  __shared__ float red[8];
  const int wid = threadIdx.x >> 6, lane = threadIdx.x & 63;
  if (!lane) { red[wid] = s; red[4 + wid] = ss; }
  __syncthreads();
  s = red[0] + red[1] + red[2] + red[3];
  ss = red[4] + red[5] + red[6] + red[7];
  const float mean = s * (1.f / 1024.f);
  const float var = ss * (1.f / 1024.f) - mean * mean;
  const float rs = rsqrtf(var + 1e-5f);
  const float4 gv = ((const float4*)g)[threadIdx.x];
  const float4 bv = ((const float4*)b)[threadIdx.x];
  ushort4 ov;
  ov.x = f2bf((v.x - mean) * rs * gv.x + bv.x);
  ov.y = f2bf((v.y - mean) * rs * gv.y + bv.y);
  ov.z = f2bf((v.z - mean) * rs * gv.z + bv.z);
  ov.w = f2bf((v.w - mean) * rs * gv.w + bv.w);
  ((ushort4*)(out + (size_t)row * 1024))[threadIdx.x] = ov;
}

// dual-output LN: one X2 read, two (g,b) sets, two bf16 outputs
__global__ __launch_bounds__(256) void ln_dual_k(
    const float* __restrict__ x, const float* __restrict__ g1, const float* __restrict__ b1,
    const float* __restrict__ g2, const float* __restrict__ b2,
    unsigned short* __restrict__ o1, unsigned short* __restrict__ o2) {
  const int row = blockIdx.x;
  const float4 v = ((const float4*)(x + (size_t)row * 1024))[threadIdx.x];
  float s = v.x + v.y + v.z + v.w;
  float ss = v.x * v.x + v.y * v.y + v.z * v.z + v.w * v.w;
#pragma unroll
  for (int o = 1; o < 64; o <<= 1) { s += __shfl_xor(s, o); ss += __shfl_xor(ss, o); }
  __shared__ float red[8];
  const int wid = threadIdx.x >> 6, lane = threadIdx.x & 63;
  if (!lane) { red[wid] = s; red[4 + wid] = ss; }
  __syncthreads();
  s = red[0] + red[1] + red[2] + red[3];
  ss = red[4] + red[5] + red[6] + red[7];
  const float mean = s * (1.f / 1024.f);
  const float var = ss * (1.f / 1024.f) - mean * mean;
  const float rs = rsqrtf(var + 1e-5f);
  const float n0 = (v.x - mean) * rs, n1 = (v.y - mean) * rs, n2 = (v.z - mean) * rs, n3 = (v.w - mean) * rs;
  {
    const float4 gv = ((const float4*)g1)[threadIdx.x];
    const float4 bv = ((const float4*)b1)[threadIdx.x];
    ushort4 ov{f2bf(n0 * gv.x + bv.x), f2bf(n1 * gv.y + bv.y), f2bf(n2 * gv.z + bv.z), f2bf(n3 * gv.w + bv.w)};
    ((ushort4*)(o1 + (size_t)row * 1024))[threadIdx.x] = ov;
  }
  {
    const float4 gv = ((const float4*)g2)[threadIdx.x];
    const float4 bv = ((const float4*)b2)[threadIdx.x];
    ushort4 ov{f2bf(n0 * gv.x + bv.x), f2bf(n1 * gv.y + bv.y), f2bf(n2 * gv.z + bv.z), f2bf(n3 * gv.w + bv.w)};
    ((ushort4*)(o2 + (size_t)row * 1024))[threadIdx.x] = ov;
  }
}

enum { EPI_NONE = 0, EPI_BIAS_RES = 1, EPI_GELU = 2, EPI_RELU = 3, EPI_SCALE_BIAS = 4, EPI_FINAL = 5 };

// ======= 8-wave pipelined GEMM; PH phases/K-tile -> 16 MFMA per phase =======
template <int BM, int BN, int EPI, typename CT>
__global__ __launch_bounds__(512, 2) void gemm8_k(
    const unsigned short* __restrict__ A, const unsigned short* __restrict__ Bt,
    CT* __restrict__ C, const float* __restrict__ bias,
    const float* __restrict__ res, const float* __restrict__ extra,
    int M, int N, int K, int gm, int gn) {
  constexpr int MF = BM / 32, NF = BN / 64;
  constexpr int PH = (MF * NF) / 8 < 1 ? 1 : (MF * NF) / 8;  // 16 MFMA per phase
  constexpr int MPP = MF / PH;
  constexpr int LA = BM / 64, LB = BN / 64;
  constexpr int BUFE = (BM + BN) * 64;
  __shared__ unsigned short lds[BUFE * 2];
  const int tid = threadIdx.x;
  const int lane = tid & 63, wid = tid >> 6;
  const int wm = wid >> 2, wn = wid & 3;
  const int l15 = lane & 15, l4 = lane >> 4;
  const int nwg = gm * gn;
  const int bid = blockIdx.x;
  const int swz = (bid % 8) * (nwg / 8) + bid / 8;  // XCD swizzle (nwg % 8 == 0)
  const int row0 = (swz / gn) * BM, col0 = (swz % gn) * BN;
  const int NT = K >> 6;

  const int srow = tid >> 3, sgr = tid & 7;
  // hoisted per-thread staging bases (T2: linear LDS dest, pre-swizzled global src)
  const unsigned short* Atb = A + (size_t)(row0 + srow) * K + ((sgr ^ (srow & 7)) << 3);
  const unsigned short* Btb = Bt + (size_t)(col0 + srow) * K + ((sgr ^ (srow & 7)) << 3);
  const size_t eStr = (size_t)64 * K;  // 64-row advance
  unsigned short* ldsA = lds + tid * 8;
  unsigned short* ldsB = lds + BM * 64 + tid * 8;

  auto stA = [&](int kt, int b, int e) {
    gload_lds16(Atb + (size_t)e * eStr + kt * 64, ldsA + b * BUFE + e * 4096);
  };
  auto stB = [&](int kt, int b, int e) {
    gload_lds16(Btb + (size_t)e * eStr + kt * 64, ldsB + b * BUFE + e * 4096);
  };

#pragma unroll
  for (int e = 0; e < LA; ++e) stA(0, 0, e);
#pragma unroll
  for (int e = 0; e < LB; ++e) stB(0, 0, e);
  if (NT > 1) {
#pragma unroll
    for (int e = 0; e < LB; ++e) stB(1, 1, e);
    asm volatile("s_waitcnt vmcnt(%0)" ::"n"(LB) : "memory");
  } else {
    asm volatile("s_waitcnt vmcnt(0)" ::: "memory");
  }
  __builtin_amdgcn_s_barrier();

  v4f acc[MF][NF] = {};
  v8s bfr[NF][2];
  for (int t = 0; t < NT; ++t) {
    const int buf = t & 1;
    const unsigned short* La = lds + buf * BUFE;
    const unsigned short* Lb = lds + buf * BUFE + BM * 64;
#pragma unroll
    for (int p = 0; p < PH; ++p) {
      if (p == 0) {  // B-frags for whole K-tile; B region free after this phase
#pragma unroll
        for (int nf = 0; nf < NF; ++nf) {
          const int r = wn * (BN / 4) + nf * 16 + l15;
#pragma unroll
          for (int kk = 0; kk < 2; ++kk)
            bfr[nf][kk] = *(const v8s*)(Lb + r * 64 + ((kk * 32 + l4 * 8) ^ ((r & 7) << 3)));
        }
      }
      v8s af[MPP][2];
#pragma unroll
      for (int mm = 0; mm < MPP; ++mm) {
        const int r = wm * (BM / 2) + (p * MPP + mm) * 16 + l15;
#pragma unroll
        for (int kk = 0; kk < 2; ++kk)
          af[mm][kk] = *(const v8s*)(La + r * 64 + ((kk * 32 + l4 * 8) ^ ((r & 7) << 3)));
      }
      // staging: p0 = all A(t+1) -> buf^1; p>=1 = B(t+2) -> buf (B region freed after p0)
      if (p == 0) {
        if (t + 1 < NT) {
#pragma unroll
          for (int e = 0; e < LA; ++e) stA(t + 1, buf ^ 1, e);
        }
      } else {
        if (t + 2 < NT) {
          constexpr int BPP = (LB + PH - 2) / (PH - 1 > 0 ? PH - 1 : 1);
#pragma unroll
          for (int e = (p - 1) * BPP; e < p * BPP && e < LB; ++e) stB(t + 2, buf, e);
        }
      }
      __builtin_amdgcn_s_barrier();
      asm volatile("s_waitcnt lgkmcnt(0)" ::: "memory");
      __builtin_amdgcn_s_setprio(1);
#pragma unroll
      for (int kk = 0; kk < 2; ++kk)  // kk OUTER: dependency distance = MPP*NF
#pragma unroll
        for (int mm = 0; mm < MPP; ++mm)
#pragma unroll
          for (int nf = 0; nf < NF; ++nf)
            acc[p * MPP + mm][nf] = __builtin_amdgcn_mfma_f32_16x16x32_bf16(
                af[mm][kk], bfr[nf][kk], acc[p * MPP + mm][nf], 0, 0, 0);
      __builtin_amdgcn_s_setprio(0);
      if (p == PH - 1 && t + 1 < NT) {
        if (t + 2 < NT) asm volatile("s_waitcnt vmcnt(%0)" ::"n"(LB) : "memory");
        else            asm volatile("s_waitcnt vmcnt(0)" ::: "memory");
      }
      __builtin_amdgcn_s_barrier();
    }
  }

#pragma unroll
  for (int mf = 0; mf < MF; ++mf) {
#pragma unroll
    for (int nf = 0; nf < NF; ++nf) {
      const int col = col0 + wn * (BN / 4) + nf * 16 + l15;
      float bv = 0.f;
      if (EPI != EPI_NONE) bv = bias[col];
#pragma unroll
      for (int j = 0; j < 4; ++j) {
        const int row = row0 + wm * (BM / 2) + mf * 16 + l4 * 4 + j;
        const size_t idx = (size_t)row * N + col;
        float v = acc[mf][nf][j];
        if (EPI == EPI_BIAS_RES) v += bv + res[idx];
        else if (EPI == EPI_GELU) { v += bv; v = 0.5f * v * (1.f + fast_erf(v * 0.70710678118f)); }
        else if (EPI == EPI_RELU) { v += bv; v = fmaxf(v, 0.f); }
        else if (EPI == EPI_SCALE_BIAS) { v = (v + bv) * 0.1f; }
        else if (EPI == EPI_FINAL) { v += bv + res[idx] + extra[idx]; }
        if constexpr (sizeof(CT) == 2) C[idx] = f2bf(v); else C[idx] = v;
      }
    }
  }
}

// ------------- small 2-phase GEMM (adapters: N=64 / K=64) -------------
template <int BN, int EPI, typename CT>
__global__ __launch_bounds__(256) void gemm_k(
    const unsigned short* __restrict__ A, const unsigned short* __restrict__ Bt,
    CT* __restrict__ C, const float* __restrict__ bias,
    const float* __restrict__ res, const float* __restrict__ extra,
    int M, int N, int K) {
  constexpr int BM = 128, BK = 32;
  constexpr int WN = (BN == 128) ? 2 : 1;
  constexpr int MR = (BN == 128) ? 4 : 2;
  constexpr int NR = 4;
  __shared__ unsigned short sA[BM * BK];
  __shared__ unsigned short sB[BN * BK];
  const int tid = threadIdx.x;
  const int lane = tid & 63, wid = tid >> 6;
  const int wm = wid / WN, wn = wid % WN;
  const int l15 = lane & 15, l4 = lane >> 4;
  const int row0 = blockIdx.x * BM, col0 = blockIdx.y * BN;
  v4f acc[MR][NR] = {};
  const int rowA = wm * MR * 16;
  const int rowB = wn * NR * 16;
  for (int k0 = 0; k0 < K; k0 += BK) {
#pragma unroll
    for (int r = 0; r < (BM * BK) / (256 * 8); ++r) {
      int e = (r * 256 + tid) * 8;
      gload_lds16(A + (size_t)(row0 + (e >> 5)) * K + k0 + (e & 31), ((unsigned short*)sA) + e);
    }
#pragma unroll
    for (int r = 0; r < (BN * BK) / (256 * 8); ++r) {
      int e = (r * 256 + tid) * 8;
      gload_lds16(Bt + (size_t)(col0 + (e >> 5)) * K + k0 + (e & 31), ((unsigned short*)sB) + e);
    }
    __syncthreads();
    v8s af[MR], bfr2[NR];
#pragma unroll
    for (int m = 0; m < MR; ++m) af[m] = *(const v8s*)(sA + (rowA + m * 16 + l15) * BK + l4 * 8);
#pragma unroll
    for (int n = 0; n < NR; ++n) bfr2[n] = *(const v8s*)(sB + (rowB + n * 16 + l15) * BK + l4 * 8);
#pragma unroll
    for (int m = 0; m < MR; ++m)
#pragma unroll
      for (int n = 0; n < NR; ++n)
        acc[m][n] = __builtin_amdgcn_mfma_f32_16x16x32_bf16(af[m], bfr2[n], acc[m][n], 0, 0, 0);
    __syncthreads();
  }
#pragma unroll
  for (int m = 0; m < MR; ++m) {
#pragma unroll
    for (int n = 0; n < NR; ++n) {
      const int col = col0 + rowB + n * 16 + l15;
      float bv = 0.f;
      if (EPI != EPI_NONE) bv = bias[col];
#pragma unroll
      for (int j = 0; j < 4; ++j) {
        const int row = row0 + rowA + m * 16 + l4 * 4 + j;
        const size_t idx = (size_t)row * N + col;
        float v = acc[m][n][j];
        if (EPI == EPI_BIAS_RES) v += bv + res[idx];
        else if (EPI == EPI_GELU) { v += bv; v = 0.5f * v * (1.f + fast_erf(v * 0.70710678118f)); }
        else if (EPI == EPI_RELU) { v += bv; v = fmaxf(v, 0.f); }
        else if (EPI == EPI_SCALE_BIAS) { v = (v + bv) * 0.1f; }
        else if (EPI == EPI_FINAL) { v += bv + res[idx] + extra[idx]; }
        if constexpr (sizeof(CT) == 2) C[idx] = f2bf(v); else C[idx] = v;
      }
    }
  }
}

// ======= flash attention: 4 waves x 32 q-rows, KVBLK=64, mfma 32x32x16, in-reg softmax =======
__global__ __launch_bounds__(256) void attn_k(
    const unsigned short* __restrict__ QKV, const unsigned short* __restrict__ VT,
    unsigned short* __restrict__ O) {
  const int bid = blockIdx.x;
  const int swz = (bid & 7) * 128 + (bid >> 3);  // XCD-local: one XCD owns 16 bh
  const int bh = swz >> 3, qb = swz & 7;
  const int b = bh >> 4, h = bh & 15;
  const int tid = threadIdx.x, lane = tid & 63, w = tid >> 6;
  const int l31 = lane & 31, hi = lane >> 5;
  __shared__ unsigned short sK[2][64 * 64];
  __shared__ unsigned short sV[2][64 * 64];
  const int q0 = qb * 128;
  const unsigned short* Qrow = QKV + (size_t)(b * 1024 + q0 + w * 32 + l31) * 3072 + h * 64;
  v8s qf[4];
#pragma unroll
  for (int kcd = 0; kcd < 4; ++kcd) qf[kcd] = *(const v8s*)(Qrow + kcd * 16 + hi * 8);

  const unsigned short* Kbase = QKV + 1024 + (size_t)(b * 1024) * 3072 + h * 64;
  const unsigned short* Vbase = VT + (size_t)bh * 64 * 1024;
  const int sr = tid >> 3, sg = tid & 7;
  // hoisted staging pointers, advanced per tile
  const unsigned short* kp0 = Kbase + (size_t)sr * 3072 + ((sg ^ (sr & 7)) << 3);
  const unsigned short* kp1 = Kbase + (size_t)(32 + sr) * 3072 + ((sg ^ (sr & 7)) << 3);
  const unsigned short* vp0 = Vbase + (size_t)sr * 1024 + ((sg ^ (sr & 7)) << 3);
  const unsigned short* vp1 = Vbase + (size_t)(32 + sr) * 1024 + ((sg ^ (sr & 7)) << 3);
  unsigned short* dK0 = &sK[0][sr * 64 + sg * 8];
  unsigned short* dK1 = &sK[0][(32 + sr) * 64 + sg * 8];
  unsigned short* dV0 = &sV[0][sr * 64 + sg * 8];
  unsigned short* dV1 = &sV[0][(32 + sr) * 64 + sg * 8];
  constexpr int BOFF = 64 * 64;  // sK[1] is exactly BOFF elements past sK[0]
  auto stage = [&](int bsel) {
    gload_lds16(kp0, dK0 + bsel * BOFF);
    gload_lds16(kp1, dK1 + bsel * BOFF);
    gload_lds16(vp0, dV0 + bsel * BOFF);
    gload_lds16(vp1, dV1 + bsel * BOFF);
    kp0 += (size_t)64 * 3072; kp1 += (size_t)64 * 3072; vp0 += 64; vp1 += 64;
  };
  stage(0);
  asm volatile("s_waitcnt vmcnt(0)" ::: "memory");
  __syncthreads();

  const float SC = 0.125f * 1.44269504f;  // scale * log2(e): softmax in exp2 domain
  float m_run = -3e38f, l_run = 0.f;
  v16f oacc0 = {}, oacc1 = {};

  for (int t = 0; t < 16; ++t) {
    const int cur = t & 1;
    if (t + 1 < 16) stage(cur ^ 1);  // issue early (T14)
    v16f s0 = {}, s1 = {};
    __builtin_amdgcn_s_setprio(1);
#pragma unroll
    for (int kcd = 0; kcd < 4; ++kcd) {
      const int c = kcd * 2 + hi;
      v8s a0 = *(const v8s*)(&sK[cur][l31 * 64 + ((c ^ (l31 & 7)) << 3)]);
      v8s a1 = *(const v8s*)(&sK[cur][(32 + l31) * 64 + ((c ^ (l31 & 7)) << 3)]);
      s0 = __builtin_amdgcn_mfma_f32_32x32x16_bf16(a0, qf[kcd], s0, 0, 0, 0);
      s1 = __builtin_amdgcn_mfma_f32_32x32x16_bf16(a1, qf[kcd], s1, 0, 0, 0);
    }
    __builtin_amdgcn_s_setprio(0);
    float p0[16], p1[16];
#pragma unroll
    for (int i = 0; i < 16; ++i) { p0[i] = s0[i] * SC; p1[i] = s1[i] * SC; }
    float mx = fmaxf(p0[0], p1[0]);
#pragma unroll
    for (int i = 1; i < 16; ++i) mx = fmaxf(mx, fmaxf(p0[i], p1[i]));
    mx = fmaxf(mx, __shfl_xor(mx, 32));
    const float m_new = fmaxf(m_run, mx);
    const float fac = exp2f(m_run - m_new);
    float ts = 0.f;
#pragma unroll
    for (int i = 0; i < 16; ++i) {
      p0[i] = exp2f(p0[i] - m_new);
      p1[i] = exp2f(p1[i] - m_new);
      ts += p0[i] + p1[i];
    }
    ts += __shfl_xor(ts, 32);
    l_run = l_run * fac + ts;
    m_run = m_new;
#pragma unroll
    for (int i = 0; i < 16; ++i) { oacc0[i] *= fac; oacc1[i] *= fac; }
    auto mkfrag = [&](const float* p, int c) -> v8s {
      unsigned A0, A1, A2, A3;
      asm("v_cvt_pk_bf16_f32 %0, %1, %2" : "=v"(A0) : "v"(p[8 * c + 0]), "v"(p[8 * c + 1]));
      asm("v_cvt_pk_bf16_f32 %0, %1, %2" : "=v"(A1) : "v"(p[8 * c + 2]), "v"(p[8 * c + 3]));
      asm("v_cvt_pk_bf16_f32 %0, %1, %2" : "=v"(A2) : "v"(p[8 * c + 4]), "v"(p[8 * c + 5]));
      asm("v_cvt_pk_bf16_f32 %0, %1, %2" : "=v"(A3) : "v"(p[8 * c + 6]), "v"(p[8 * c + 7]));
      asm("v_permlane32_swap_b32 %0, %1" : "+v"(A2), "+v"(A0));
      asm("v_permlane32_swap_b32 %0, %1" : "+v"(A3), "+v"(A1));
      union { unsigned u[4]; v8s v; } r;
      r.u[0] = A0; r.u[1] = A1; r.u[2] = A2; r.u[3] = A3;
      return r.v;
    };
    v8s pB0 = mkfrag(p0, 0), pB1 = mkfrag(p0, 1), pB2 = mkfrag(p1, 0), pB3 = mkfrag(p1, 1);
    __builtin_amdgcn_s_setprio(1);
#pragma unroll
    for (int kc = 0; kc < 4; ++kc) {
      const v8s pb = (kc == 0) ? pB0 : (kc == 1) ? pB1 : (kc == 2) ? pB2 : pB3;
      const int c = kc * 2 + hi;
      v8s vf0 = *(const v8s*)(&sV[cur][l31 * 64 + ((c ^ (l31 & 7)) << 3)]);
      v8s vf1 = *(const v8s*)(&sV[cur][(32 + l31) * 64 + ((c ^ (l31 & 7)) << 3)]);
      oacc0 = __builtin_amdgcn_mfma_f32_32x32x16_bf16(vf0, pb, oacc0, 0, 0, 0);
      oacc1 = __builtin_amdgcn_mfma_f32_32x32x16_bf16(vf1, pb, oacc1, 0, 0, 0);
    }
    __builtin_amdgcn_s_setprio(0);
    if (t + 1 < 16) {
      asm volatile("s_waitcnt vmcnt(0)" ::: "memory");
      __syncthreads();
    }
  }
  const float inv = 1.f / l_run;
  unsigned short* Orow = O + (size_t)(b * 1024 + q0 + w * 32 + l31) * 1024 + h * 64;
#pragma unroll
  for (int g = 0; g < 4; ++g) {
    ushort4 st0{f2bf(oacc0[4 * g + 0] * inv), f2bf(oacc0[4 * g + 1] * inv),
                f2bf(oacc0[4 * g + 2] * inv), f2bf(oacc0[4 * g + 3] * inv)};
    ushort4 st1{f2bf(oacc1[4 * g + 0] * inv), f2bf(oacc1[4 * g + 1] * inv),
                f2bf(oacc1[4 * g + 2] * inv), f2bf(oacc1[4 * g + 3] * inv)};
    *(ushort4*)(Orow + g * 8 + hi * 4) = st0;
    *(ushort4*)(Orow + 32 + g * 8 + hi * 4) = st1;
  }
}

// ---------------- launch ----------------
extern "C" void kernel_launch(void* const* d_in, const int* in_sizes, int n_in,
                              void* d_out, int out_size, void* d_ws, size_t ws_size,
                              hipStream_t stream) {
  (void)in_sizes; (void)n_in; (void)out_size;
  const float* x    = (const float*)d_in[0];
  const float* ln1g = (const float*)d_in[1];
  const float* ln1b = (const float*)d_in[2];
  const float* wq   = (const float*)d_in[3];
  const float* wk   = (const float*)d_in[4];
  const float* wv   = (const float*)d_in[5];
  const float* wo   = (const float*)d_in[6];
  const float* bo   = (const float*)d_in[7];
  const float* ln2g = (const float*)d_in[8];
  const float* ln2b = (const float*)d_in[9];
  const float* w1   = (const float*)d_in[10];
  const float* b1   = (const float*)d_in[11];
  const float* w2   = (const float*)d_in[12];
  const float* b2   = (const float*)d_in[13];
  const float* alng = (const float*)d_in[14];
  const float* alnb = (const float*)d_in[15];
  const float* wd   = (const float*)d_in[16];
  const float* bd   = (const float*)d_in[17];
  const float* wu   = (const float*)d_in[18];
  const float* bu   = (const float*)d_in[19];
  float* out = (float*)d_out;

  char* W = (char*)d_ws;
  size_t off = 0;
  auto allocB = [&](size_t bytes) { void* p = W + off; off += (bytes + 255) & ~(size_t)255; return p; };
  const size_t T = 8192;
  unsigned short* wqkvt = (unsigned short*)allocB((size_t)3072 * 1024 * 2);
  unsigned short* wot   = (unsigned short*)allocB((size_t)1024 * 1024 * 2);
  unsigned short* w1t   = (unsigned short*)allocB((size_t)4096 * 1024 * 2);
  unsigned short* w2t   = (unsigned short*)allocB((size_t)4096 * 1024 * 2);
  unsigned short* wdt   = (unsigned short*)allocB(64 * 1024 * 2);
  unsigned short* wut   = (unsigned short*)allocB(64 * 1024 * 2);
  unsigned short* H     = (unsigned short*)allocB(T * 1024 * 2);
  unsigned short* H2    = (unsigned short*)allocB(T * 1024 * 2);
  unsigned short* QKV   = (unsigned short*)allocB(T * 3072 * 2);
  unsigned short* VT    = (unsigned short*)allocB(T * 1024 * 2);
  float* X2             = (float*)allocB(T * 1024 * 4);
  unsigned short* MID   = (unsigned short*)allocB(T * 4096 * 2);
  unsigned short* AO  = MID;          // attn out, dead before FFN1 writes MID
  unsigned short* DWN = VT;           // adapter-down out, VT dead after attn
  float* ADP          = (float*)QKV;  // adapter-up out fp32, QKV dead after attn
  if (ws_size < off) return;

  dim3 blk(256);
  transpose_cvt_k<<<dim3(32, 32), blk, 0, stream>>>(wq, wqkvt, 1024, 1024);
  transpose_cvt_k<<<dim3(32, 32), blk, 0, stream>>>(wk, wqkvt + (size_t)1024 * 1024, 1024, 1024);
  transpose_cvt_k<<<dim3(32, 32), blk, 0, stream>>>(wv, wqkvt + (size_t)2048 * 1024, 1024, 1024);
  transpose_cvt_k<<<dim3(32, 32), blk, 0, stream>>>(wo, wot, 1024, 1024);
  transpose_cvt_k<<<dim3(128, 32), blk, 0, stream>>>(w1, w1t, 1024, 4096);
  transpose_cvt_k<<<dim3(32, 128), blk, 0, stream>>>(w2, w2t, 4096, 1024);
  transpose_cvt_k<<<dim3(2, 32), blk, 0, stream>>>(wd, wdt, 1024, 64);
  transpose_cvt_k<<<dim3(32, 2), blk, 0, stream>>>(wu, wut, 64, 1024);

  ln_k<<<8192, blk, 0, stream>>>(x, ln1g, ln1b, H);
  gemm8_k<128, 256, EPI_NONE, unsigned short><<<768, 512, 0, stream>>>(
      H, wqkvt, QKV, nullptr, nullptr, nullptr, 8192, 3072, 1024, 64, 12);
  vtrans_k<<<dim3(32, 2, 128), blk, 0, stream>>>(QKV + 2048, VT, 3072);
  attn_k<<<1024, blk, 0, stream>>>(QKV, VT, AO);
  gemm8_k<128, 256, EPI_BIAS_RES, float><<<256, 512, 0, stream>>>(
      AO, wot, X2, bo, x, nullptr, 8192, 1024, 1024, 64, 4);
  ln_dual_k<<<8192, blk, 0, stream>>>(X2, alng, alnb, ln2g, ln2b, H, H2);
  gemm_k<64, EPI_RELU, unsigned short><<<dim3(64, 1), blk, 0, stream>>>(
      H, wdt, DWN, bd, nullptr, nullptr, 8192, 64, 1024);
  gemm_k<128, EPI_SCALE_BIAS, float><<<dim3(64, 8), blk, 0, stream>>>(
      DWN, wut, ADP, bu, nullptr, nullptr, 8192, 1024, 64);
  gemm8_k<256, 256, EPI_GELU, unsigned short><<<512, 512, 0, stream>>>(
      H2, w1t, MID, b1, nullptr, nullptr, 8192, 4096, 1024, 32, 16);
  gemm8_k<128, 256, EPI_FINAL, float><<<256, 512, 0, stream>>>(
      MID, w2t, out, b2, X2, ADP, 8192, 1024, 4096, 64, 4);
}